// Round 7
// baseline (158.371 us; speedup 1.0000x reference)
//
#include <hip/hip_runtime.h>

// ---------------------------------------------------------------------------
// FakeFusedMoE: E=8, H=1024, F=1024, top-2, N=2048 tokens (4096 routed rows).
// Sparse grouped-GEMM MoE, bf16 MFMA.
//   k_pre       : convert gu fp32->bf16 (blocks 0..8191) ++ router+hidden cvt
//   k_build_perm: counting-sort + PER-XCD work queues (expert e -> XCD e, so
//                 panel re-reads hit XCD-local L2 instead of saturating L3)
//   k_gemm1     : counted-vmcnt 2-deep pipeline (R5-proven) ++ dp fp32->bf16
//                 conversion folded into trailing blocks (runs concurrently)
//   k_gemm2     : same structure, per-XCD queue
//   k_combine   : out[n] = partial[2n] + partial[2n+1]
// ---------------------------------------------------------------------------

#define NTOK   2048
#define HDIM   1024
#define FDIM   1024
#define NEXP   8
#define NKROWS 4096
#define Q1LEN  160    // per-XCD gemm1 queue capacity (rt<=10 x 16 cols)
#define Q2LEN  80     // per-XCD gemm2 queue capacity (rt<=10 x 8 cols)

typedef __attribute__((ext_vector_type(8))) __bf16 bf16x8;
typedef __attribute__((ext_vector_type(4))) float  floatx4;

__device__ __forceinline__ unsigned short f2bf(float x) {
    unsigned int u = __builtin_bit_cast(unsigned int, x);
    u += 0x7FFFu + ((u >> 16) & 1u);
    return (unsigned short)(u >> 16);
}

__device__ __forceinline__ float bf2f(unsigned short v) {
    unsigned int u = (unsigned int)v << 16;
    return __builtin_bit_cast(float, u);
}

__device__ __forceinline__ uint4 pack8(float4 a, float4 b) {
    uint4 o;
    o.x = (unsigned)f2bf(a.x) | ((unsigned)f2bf(a.y) << 16);
    o.y = (unsigned)f2bf(a.z) | ((unsigned)f2bf(a.w) << 16);
    o.z = (unsigned)f2bf(b.x) | ((unsigned)f2bf(b.y) << 16);
    o.w = (unsigned)f2bf(b.z) | ((unsigned)f2bf(b.w) << 16);
    return o;
}

// async global->LDS, 16B/lane; LDS dest = wave-uniform base + lane*16
__device__ __forceinline__ void dma16(const void* g, void* l) {
    __builtin_amdgcn_global_load_lds(
        (const __attribute__((address_space(1))) unsigned int*)g,
        (__attribute__((address_space(3))) unsigned int*)l, 16, 0, 0);
}

// ---------------------------------------------------------------------------
// Fused: gu fp32->bf16 streaming convert (blocks 0..8191) + router (512 blocks).
__global__ __launch_bounds__(256) void k_pre(
    const float* __restrict__ gu, unsigned short* __restrict__ gubf,
    const float* __restrict__ h, const float* __restrict__ rw,
    unsigned short* __restrict__ hbf,
    int* __restrict__ topk_idx, float* __restrict__ topk_w)
{
    const int b = blockIdx.x;
    if (b < 8192) {                       // gu convert: 2048 elems/block
        size_t i = (size_t)b * 2048 + (size_t)threadIdx.x * 8;
        const float4* s = reinterpret_cast<const float4*>(gu + i);
        float4 a = s[0], c = s[1];
        *reinterpret_cast<uint4*>(gubf + i) = pack8(a, c);
        return;
    }
    // ---- router: one wave per token, 4 tokens per block
    const int lane = threadIdx.x & 63;
    const int wave = threadIdx.x >> 6;
    const int n = (b - 8192) * 4 + wave;

    const float4* hp = reinterpret_cast<const float4*>(h + (size_t)n * HDIM);
    uint2* hb = reinterpret_cast<uint2*>(hbf + (size_t)n * HDIM);
    float acc[NEXP];
#pragma unroll
    for (int e = 0; e < NEXP; ++e) acc[e] = 0.f;

#pragma unroll
    for (int i0 = 0; i0 < HDIM / 4; i0 += 64) {
        float4 hv = hp[i0 + lane];
        uint2 o;
        o.x = (unsigned)f2bf(hv.x) | ((unsigned)f2bf(hv.y) << 16);
        o.y = (unsigned)f2bf(hv.z) | ((unsigned)f2bf(hv.w) << 16);
        hb[i0 + lane] = o;
#pragma unroll
        for (int e = 0; e < NEXP; ++e) {
            float4 rv = reinterpret_cast<const float4*>(rw + e * HDIM)[i0 + lane];
            acc[e] += hv.x * rv.x + hv.y * rv.y + hv.z * rv.z + hv.w * rv.w;
        }
    }
#pragma unroll
    for (int e = 0; e < NEXP; ++e) {
#pragma unroll
        for (int off = 32; off > 0; off >>= 1)
            acc[e] += __shfl_xor(acc[e], off);
    }
    if (lane == 0) {
        int i0 = 0; float m0 = acc[0];
        for (int e = 1; e < NEXP; ++e) if (acc[e] > m0) { m0 = acc[e]; i0 = e; }
        int i1 = -1; float m1 = -3.0e38f;
        for (int e = 0; e < NEXP; ++e) if (e != i0 && acc[e] > m1) { m1 = acc[e]; i1 = e; }
        float d  = __expf(m1 - m0);
        float w0 = 1.f / (1.f + d);
        topk_idx[n * 2 + 0] = i0;
        topk_idx[n * 2 + 1] = i1;
        topk_w [n * 2 + 0] = w0;
        topk_w [n * 2 + 1] = 1.f - w0;
    }
}

// ---------------------------------------------------------------------------
// Counting-sort permutation + per-XCD work queues.
// Queue entry: e | (rowTile<<4) | (colTile<<9); -1 = empty.
// Col-major order within a queue so concurrently-running blocks share B-panels.
__global__ __launch_bounds__(256) void k_build_perm(
    const int* __restrict__ topk_idx, const float* __restrict__ topk_w,
    int* __restrict__ offsets, int* __restrict__ perm_slot, float* __restrict__ row_w,
    int* __restrict__ q1, int* __restrict__ q2)
{
    __shared__ int cnt[NEXP];
    __shared__ int cur[NEXP];
    __shared__ int off[NEXP + 1];
    const int t = threadIdx.x;
    if (t < NEXP) cnt[t] = 0;
    __syncthreads();
    for (int s = t; s < NKROWS; s += 256) atomicAdd(&cnt[topk_idx[s]], 1);
    __syncthreads();
    if (t == 0) {
        int a = 0;
        for (int e = 0; e < NEXP; ++e) { off[e] = a; a += cnt[e]; cur[e] = off[e]; }
        off[NEXP] = a;
        for (int e = 0; e < NEXP; ++e) {
            int rts = (cnt[e] + 127) >> 7;          // 128-row tiles
            int k = 0;
            for (int col = 0; col < 16; ++col)       // gemm1: 16 col tiles of 64
                for (int r = 0; r < rts; ++r)
                    if (k < Q1LEN) q1[e * Q1LEN + k++] = e | (r << 4) | (col << 9);
            for (; k < Q1LEN; ++k) q1[e * Q1LEN + k] = -1;
            k = 0;
            for (int col = 0; col < 8; ++col)        // gemm2: 8 col tiles of 128
                for (int r = 0; r < rts; ++r)
                    if (k < Q2LEN) q2[e * Q2LEN + k++] = e | (r << 4) | (col << 9);
            for (; k < Q2LEN; ++k) q2[e * Q2LEN + k] = -1;
        }
    }
    __syncthreads();
    for (int s = t; s < NKROWS; s += 256) {
        int e = topk_idx[s];
        int pos = atomicAdd(&cur[e], 1);
        perm_slot[pos] = s;
        row_w[pos] = topk_w[s];
    }
    if (t < NEXP + 1) offsets[t] = off[t];
}

// ---------------------------------------------------------------------------
// GEMM1: act[p][f] = silu(gate)*up. Block 128 rows x 64 f-cols (gate AND up).
// 4 waves (2x2). 2-deep DMA prefetch, counted vmcnt(8), raw barriers.
// Trailing blocks (bid >= 8*Q1LEN) convert dp fp32->bf16 concurrently.
__global__ __launch_bounds__(256, 2) void k_gemm1(
    const unsigned short* __restrict__ hbf, const unsigned short* __restrict__ gubf,
    const int* __restrict__ offsets, const int* __restrict__ perm_slot,
    const int* __restrict__ q1,
    const float* __restrict__ dp, unsigned short* __restrict__ dpbf,
    unsigned short* __restrict__ act)
{
    const int bid = blockIdx.x;
    if (bid >= 8 * Q1LEN) {               // dp convert: 2048 elems/block
        size_t i = (size_t)(bid - 8 * Q1LEN) * 2048 + (size_t)threadIdx.x * 8;
        const float4* s = reinterpret_cast<const float4*>(dp + i);
        float4 a = s[0], c = s[1];
        *reinterpret_cast<uint4*>(dpbf + i) = pack8(a, c);
        return;
    }
    const int q = q1[(bid & 7) * Q1LEN + (bid >> 3)];   // XCD-local queue
    if (q < 0) return;
    const int e  = q & 15;
    const int rt = (q >> 4) & 31;
    const int c0 = (q >> 9) * 64;
    const int off_e = offsets[e];
    const int n_e   = offsets[e + 1] - off_e;
    const int p0 = off_e + rt * 128;
    const int nr = min(128, n_e - rt * 128);

    __shared__ __align__(16) char smA [2][128 * 128];   // bf16 128r x 64K
    __shared__ __align__(16) char smBg[2][64 * 128];
    __shared__ __align__(16) char smBu[2][64 * 128];
    __shared__ int sTok[128];

    const int t = threadIdx.x;
    const int lane = t & 63;
    const int wv = t >> 6;
    const int wr = wv >> 1, wc = wv & 1;
    if (t < 128) sTok[t] = perm_slot[min(p0 + t, NKROWS - 1)] >> 1;
    __syncthreads();

    const int rin = lane >> 3;
    const int pre = ((lane & 7) << 4) ^ (rin << 4);   // pre-swizzled source byte

    const char* asrc[4];
    int aldo[4];
#pragma unroll
    for (int c = 0; c < 4; ++c) {
        int ch = wv * 4 + c;
        int row = ch * 8 + rin;
        asrc[c] = (const char*)(hbf + (size_t)sTok[row] * HDIM) + pre;
        aldo[c] = ch * 1024;
    }
    const unsigned short* guE = gubf + (size_t)e * (2 * FDIM) * HDIM;
    const char* gsrc[2];
    const char* usrc[2];
    int bldo[2];
#pragma unroll
    for (int c = 0; c < 2; ++c) {
        int ch = wv * 2 + c;
        int col = ch * 8 + rin;
        gsrc[c] = (const char*)(guE + (size_t)(c0 + col) * HDIM) + pre;
        usrc[c] = (const char*)(guE + (size_t)(FDIM + c0 + col) * HDIM) + pre;
        bldo[c] = ch * 1024;
    }

    floatx4 accg[4][2], accu[4][2];
#pragma unroll
    for (int m = 0; m < 4; ++m)
#pragma unroll
        for (int nn = 0; nn < 2; ++nn) { accg[m][nn] = (floatx4)0.f; accu[m][nn] = (floatx4)0.f; }

#define STAGE1(k0, buf)                                                         \
    {                                                                           \
        _Pragma("unroll")                                                       \
        for (int c = 0; c < 4; ++c) dma16(asrc[c] + (size_t)(k0) * 2, smA [buf] + aldo[c]); \
        _Pragma("unroll")                                                       \
        for (int c = 0; c < 2; ++c) dma16(gsrc[c] + (size_t)(k0) * 2, smBg[buf] + bldo[c]); \
        _Pragma("unroll")                                                       \
        for (int c = 0; c < 2; ++c) dma16(usrc[c] + (size_t)(k0) * 2, smBu[buf] + bldo[c]); \
    }

    STAGE1(0, 0);
    STAGE1(64, 1);

    for (int step = 0; step < 16; ++step) {
        if (step < 15) asm volatile("s_waitcnt vmcnt(8)" ::: "memory");
        else           asm volatile("s_waitcnt vmcnt(0)" ::: "memory");
        __builtin_amdgcn_s_barrier();
        __builtin_amdgcn_sched_barrier(0);
        const int cur = step & 1;
#pragma unroll
        for (int kk = 0; kk < 2; ++kk) {
            const int kA = kk * 64 + (lane >> 4) * 16;
            bf16x8 a[4], fg[2], fu[2];
#pragma unroll
            for (int m = 0; m < 4; ++m) {
                int row = wr * 64 + m * 16 + (lane & 15);
                a[m] = *reinterpret_cast<const bf16x8*>(&smA[cur][row * 128 + (kA ^ ((row & 7) << 4))]);
            }
#pragma unroll
            for (int nn = 0; nn < 2; ++nn) {
                int cc = wc * 32 + nn * 16 + (lane & 15);
                int ad = cc * 128 + (kA ^ ((cc & 7) << 4));
                fg[nn] = *reinterpret_cast<const bf16x8*>(&smBg[cur][ad]);
                fu[nn] = *reinterpret_cast<const bf16x8*>(&smBu[cur][ad]);
            }
#pragma unroll
            for (int m = 0; m < 4; ++m)
#pragma unroll
                for (int nn = 0; nn < 2; ++nn) {
                    accg[m][nn] = __builtin_amdgcn_mfma_f32_16x16x32_bf16(a[m], fg[nn], accg[m][nn], 0, 0, 0);
                    accu[m][nn] = __builtin_amdgcn_mfma_f32_16x16x32_bf16(a[m], fu[nn], accu[m][nn], 0, 0, 0);
                }
        }
        __builtin_amdgcn_sched_barrier(0);
        __builtin_amdgcn_s_barrier();            // all waves done reading buf cur
        if (step < 14) STAGE1((step + 2) * 64, cur);
    }
#undef STAGE1

    // epilogue: silu(gate) * up -> act (bf16)
#pragma unroll
    for (int m = 0; m < 4; ++m)
#pragma unroll
        for (int nn = 0; nn < 2; ++nn)
#pragma unroll
            for (int j = 0; j < 4; ++j) {
                int rr = wr * 64 + m * 16 + ((lane >> 4) << 2) + j;
                if (rr < nr) {
                    int f = c0 + wc * 32 + nn * 16 + (lane & 15);
                    float gg = accg[m][nn][j];
                    float uu = accu[m][nn][j];
                    float s = gg / (1.f + __expf(-gg));
                    act[(size_t)(p0 + rr) * FDIM + f] = f2bf(s * uu);
                }
            }
}

// ---------------------------------------------------------------------------
// GEMM2: partial[slot][h] = w * (act_row . dp[e][h][:]), bf16 out.
// Block 128 rows x 128 h-cols; 4 waves (2x2), wave 64x64, acc[4][4].
__global__ __launch_bounds__(256, 2) void k_gemm2(
    const unsigned short* __restrict__ act, const unsigned short* __restrict__ dpbf,
    const int* __restrict__ offsets, const int* __restrict__ perm_slot,
    const int* __restrict__ q2,
    const float* __restrict__ row_w, unsigned short* __restrict__ partial)
{
    const int bid = blockIdx.x;
    const int q = q2[(bid & 7) * Q2LEN + (bid >> 3)];   // XCD-local queue
    if (q < 0) return;
    const int e  = q & 15;
    const int rt = (q >> 4) & 31;
    const int c0 = (q >> 9) * 128;
    const int off_e = offsets[e];
    const int n_e   = offsets[e + 1] - off_e;
    const int p0 = off_e + rt * 128;
    const int nr = min(128, n_e - rt * 128);

    __shared__ __align__(16) char smA[2][128 * 128];
    __shared__ __align__(16) char smB[2][128 * 128];
    __shared__ int   sSlot[128];
    __shared__ float sW[128];

    const int t = threadIdx.x;
    const int lane = t & 63;
    const int wv = t >> 6;
    const int wr = wv >> 1, wc = wv & 1;
    if (t < 128) {
        int p = min(p0 + t, NKROWS - 1);
        sSlot[t] = perm_slot[p];
        sW[t]    = row_w[p];
    }
    __syncthreads();

    const int rin = lane >> 3;
    const int pre = ((lane & 7) << 4) ^ (rin << 4);

    const char* asrc[4];
    int aldo[4];
#pragma unroll
    for (int c = 0; c < 4; ++c) {
        int ch = wv * 4 + c;
        int row = ch * 8 + rin;
        int p = min(p0 + row, NKROWS - 1);
        asrc[c] = (const char*)(act + (size_t)p * FDIM) + pre;
        aldo[c] = ch * 1024;
    }
    const unsigned short* dpE = dpbf + (size_t)e * HDIM * FDIM;
    const char* bsrc[4];
    int bldo[4];
#pragma unroll
    for (int c = 0; c < 4; ++c) {
        int ch = wv * 4 + c;
        int col = ch * 8 + rin;
        bsrc[c] = (const char*)(dpE + (size_t)(c0 + col) * FDIM) + pre;
        bldo[c] = ch * 1024;
    }

    floatx4 acc[4][4];
#pragma unroll
    for (int m = 0; m < 4; ++m)
#pragma unroll
        for (int nn = 0; nn < 4; ++nn) acc[m][nn] = (floatx4)0.f;

#define STAGE2(k0, buf)                                                         \
    {                                                                           \
        _Pragma("unroll")                                                       \
        for (int c = 0; c < 4; ++c) dma16(asrc[c] + (size_t)(k0) * 2, smA[buf] + aldo[c]); \
        _Pragma("unroll")                                                       \
        for (int c = 0; c < 4; ++c) dma16(bsrc[c] + (size_t)(k0) * 2, smB[buf] + bldo[c]); \
    }

    STAGE2(0, 0);
    STAGE2(64, 1);

    for (int step = 0; step < 16; ++step) {
        if (step < 15) asm volatile("s_waitcnt vmcnt(8)" ::: "memory");
        else           asm volatile("s_waitcnt vmcnt(0)" ::: "memory");
        __builtin_amdgcn_s_barrier();
        __builtin_amdgcn_sched_barrier(0);
        const int cur = step & 1;
#pragma unroll
        for (int kk = 0; kk < 2; ++kk) {
            const int kA = kk * 64 + (lane >> 4) * 16;
            bf16x8 a[4], fb[4];
#pragma unroll
            for (int m = 0; m < 4; ++m) {
                int row = wr * 64 + m * 16 + (lane & 15);
                a[m] = *reinterpret_cast<const bf16x8*>(&smA[cur][row * 128 + (kA ^ ((row & 7) << 4))]);
            }
#pragma unroll
            for (int nn = 0; nn < 4; ++nn) {
                int cc = wc * 64 + nn * 16 + (lane & 15);
                fb[nn] = *reinterpret_cast<const bf16x8*>(&smB[cur][cc * 128 + (kA ^ ((cc & 7) << 4))]);
            }
#pragma unroll
            for (int m = 0; m < 4; ++m)
#pragma unroll
                for (int nn = 0; nn < 4; ++nn)
                    acc[m][nn] = __builtin_amdgcn_mfma_f32_16x16x32_bf16(a[m], fb[nn], acc[m][nn], 0, 0, 0);
        }
        __builtin_amdgcn_sched_barrier(0);
        __builtin_amdgcn_s_barrier();
        if (step < 14) STAGE2((step + 2) * 64, cur);
    }
#undef STAGE2

#pragma unroll
    for (int m = 0; m < 4; ++m)
#pragma unroll
        for (int nn = 0; nn < 4; ++nn)
#pragma unroll
            for (int j = 0; j < 4; ++j) {
                int rr = wr * 64 + m * 16 + ((lane >> 4) << 2) + j;
                if (rr < nr) {
                    int hcol = c0 + wc * 64 + nn * 16 + (lane & 15);
                    partial[(size_t)sSlot[rr] * HDIM + hcol] = f2bf(sW[rr] * acc[m][nn][j]);
                }
            }
}

// ---------------------------------------------------------------------------
// out[n][h] = partial[2n][h] + partial[2n+1][h]  (bf16 -> fp32)
__global__ __launch_bounds__(256) void k_combine(
    const unsigned short* __restrict__ partial, float* __restrict__ out)
{
    int gid = blockIdx.x * 256 + threadIdx.x;   // NTOK * H / 8 = 262144
    int n = gid >> 7;
    int r = gid & 127;
    uint4 a = reinterpret_cast<const uint4*>(partial + (size_t)(2 * n) * HDIM)[r];
    uint4 b = reinterpret_cast<const uint4*>(partial + (size_t)(2 * n + 1) * HDIM)[r];
    float4 o0, o1;
    o0.x = bf2f(a.x & 0xFFFF) + bf2f(b.x & 0xFFFF);
    o0.y = bf2f(a.x >> 16)    + bf2f(b.x >> 16);
    o0.z = bf2f(a.y & 0xFFFF) + bf2f(b.y & 0xFFFF);
    o0.w = bf2f(a.y >> 16)    + bf2f(b.y >> 16);
    o1.x = bf2f(a.z & 0xFFFF) + bf2f(b.z & 0xFFFF);
    o1.y = bf2f(a.z >> 16)    + bf2f(b.z >> 16);
    o1.z = bf2f(a.w & 0xFFFF) + bf2f(b.w & 0xFFFF);
    o1.w = bf2f(a.w >> 16)    + bf2f(b.w >> 16);
    float4* op = reinterpret_cast<float4*>(out + (size_t)n * HDIM + r * 8);
    op[0] = o0;
    op[1] = o1;
}

// ---------------------------------------------------------------------------
extern "C" void kernel_launch(void* const* d_in, const int* in_sizes, int n_in,
                              void* d_out, int out_size, void* d_ws, size_t ws_size,
                              hipStream_t stream)
{
    const float* h  = (const float*)d_in[0];
    const float* rw = (const float*)d_in[1];
    const float* gu = (const float*)d_in[2];
    const float* dp = (const float*)d_in[3];
    float* out = (float*)d_out;

    char* ws = (char*)d_ws;
    int*            topk_idx  = (int*)   (ws + 0);
    float*          topk_w    = (float*) (ws + 16384);
    int*            offsets   = (int*)   (ws + 32768);
    int*            perm_slot = (int*)   (ws + 36864);
    float*          row_w     = (float*) (ws + 53248);
    int*            q1        = (int*)   (ws + 69632);   // 8*160*4 = 5120 B
    int*            q2        = (int*)   (ws + 74752);   // 8*80*4  = 2560 B
    unsigned short* hbf       = (unsigned short*)(ws + (1u  << 20));  // 8MB
    unsigned short* partial   = (unsigned short*)(ws + (1u  << 20));  // overlays hbf (dead after gemm1)
    unsigned short* act       = (unsigned short*)(ws + (9u  << 20));  // 8MB
    unsigned short* gubf      = (unsigned short*)(ws + (17u << 20));  // 32MB
    unsigned short* dpbf      = (unsigned short*)(ws + (49u << 20));  // 16MB

    hipLaunchKernelGGL(k_pre,        dim3(8704),            dim3(256), 0, stream, gu, gubf, h, rw, hbf, topk_idx, topk_w);
    hipLaunchKernelGGL(k_build_perm, dim3(1),               dim3(256), 0, stream, topk_idx, topk_w, offsets, perm_slot, row_w, q1, q2);
    hipLaunchKernelGGL(k_gemm1,      dim3(8 * Q1LEN + 4096), dim3(256), 0, stream, hbf, gubf, offsets, perm_slot, q1, dp, dpbf, act);
    hipLaunchKernelGGL(k_gemm2,      dim3(8 * Q2LEN),        dim3(256), 0, stream, act, dpbf, offsets, perm_slot, q2, row_w, partial);
    hipLaunchKernelGGL(k_combine,    dim3(1024),            dim3(256), 0, stream, partial, out);
}

// Round 8
// 107.616 us; speedup vs baseline: 1.4716x; 1.4716x over previous
//
#include <hip/hip_runtime.h>

// ---------------------------------------------------------------------------
// FakeFusedMoE: E=8, H=1024, F=1024, top-2, N=2048 tokens (4096 routed rows).
// Sparse grouped-GEMM MoE, bf16 MFMA.
//   k_pre       : convert gu+dp fp32->bf16 (streaming) ++ router+hidden cvt
//   k_build_perm: counting-sort + PER-XCD work queues (expert e -> XCD e),
//                 queue build fully parallelized (R6 lesson: serial t==0
//                 queue build was 70us of single-lane work)
//   k_gemm1/2   : counted-vmcnt 2-deep pipeline (R5-proven), XCD-local queue
//   k_combine   : out[n] = partial[2n] + partial[2n+1]
// ---------------------------------------------------------------------------

#define NTOK   2048
#define HDIM   1024
#define FDIM   1024
#define NEXP   8
#define NKROWS 4096
#define Q1LEN  256    // per-XCD gemm1 queue (16 cols x up to 16 row tiles)
#define Q2LEN  128    // per-XCD gemm2 queue (8 cols x up to 16 row tiles)

typedef __attribute__((ext_vector_type(8))) __bf16 bf16x8;
typedef __attribute__((ext_vector_type(4))) float  floatx4;

__device__ __forceinline__ unsigned short f2bf(float x) {
    unsigned int u = __builtin_bit_cast(unsigned int, x);
    u += 0x7FFFu + ((u >> 16) & 1u);
    return (unsigned short)(u >> 16);
}

__device__ __forceinline__ float bf2f(unsigned short v) {
    unsigned int u = (unsigned int)v << 16;
    return __builtin_bit_cast(float, u);
}

__device__ __forceinline__ uint4 pack8(float4 a, float4 b) {
    uint4 o;
    o.x = (unsigned)f2bf(a.x) | ((unsigned)f2bf(a.y) << 16);
    o.y = (unsigned)f2bf(a.z) | ((unsigned)f2bf(a.w) << 16);
    o.z = (unsigned)f2bf(b.x) | ((unsigned)f2bf(b.y) << 16);
    o.w = (unsigned)f2bf(b.z) | ((unsigned)f2bf(b.w) << 16);
    return o;
}

// async global->LDS, 16B/lane; LDS dest = wave-uniform base + lane*16
__device__ __forceinline__ void dma16(const void* g, void* l) {
    __builtin_amdgcn_global_load_lds(
        (const __attribute__((address_space(1))) unsigned int*)g,
        (__attribute__((address_space(3))) unsigned int*)l, 16, 0, 0);
}

// ---------------------------------------------------------------------------
// Fused streaming pre-pass:
//   blocks [0,8192)      : gu fp32->bf16   (2048 elems each)
//   blocks [8192,12288)  : dp fp32->bf16
//   blocks [12288,12800) : router, one wave per token
__global__ __launch_bounds__(256) void k_pre(
    const float* __restrict__ gu, unsigned short* __restrict__ gubf,
    const float* __restrict__ dp, unsigned short* __restrict__ dpbf,
    const float* __restrict__ h, const float* __restrict__ rw,
    unsigned short* __restrict__ hbf,
    int* __restrict__ topk_idx, float* __restrict__ topk_w)
{
    const int b = blockIdx.x;
    if (b < 12288) {
        const float* src;
        unsigned short* dst;
        size_t base;
        if (b < 8192) { base = (size_t)b * 2048;          src = gu; dst = gubf; }
        else          { base = (size_t)(b - 8192) * 2048; src = dp; dst = dpbf; }
        size_t i = base + (size_t)threadIdx.x * 8;
        const float4* s = reinterpret_cast<const float4*>(src + i);
        float4 a = s[0], c = s[1];
        *reinterpret_cast<uint4*>(dst + i) = pack8(a, c);
        return;
    }
    // ---- router
    const int lane = threadIdx.x & 63;
    const int wave = threadIdx.x >> 6;
    const int n = (b - 12288) * 4 + wave;

    const float4* hp = reinterpret_cast<const float4*>(h + (size_t)n * HDIM);
    uint2* hb = reinterpret_cast<uint2*>(hbf + (size_t)n * HDIM);
    float acc[NEXP];
#pragma unroll
    for (int e = 0; e < NEXP; ++e) acc[e] = 0.f;

#pragma unroll
    for (int i0 = 0; i0 < HDIM / 4; i0 += 64) {
        float4 hv = hp[i0 + lane];
        uint2 o;
        o.x = (unsigned)f2bf(hv.x) | ((unsigned)f2bf(hv.y) << 16);
        o.y = (unsigned)f2bf(hv.z) | ((unsigned)f2bf(hv.w) << 16);
        hb[i0 + lane] = o;
#pragma unroll
        for (int e = 0; e < NEXP; ++e) {
            float4 rv = reinterpret_cast<const float4*>(rw + e * HDIM)[i0 + lane];
            acc[e] += hv.x * rv.x + hv.y * rv.y + hv.z * rv.z + hv.w * rv.w;
        }
    }
#pragma unroll
    for (int e = 0; e < NEXP; ++e) {
#pragma unroll
        for (int off = 32; off > 0; off >>= 1)
            acc[e] += __shfl_xor(acc[e], off);
    }
    if (lane == 0) {
        int i0 = 0; float m0 = acc[0];
        for (int e = 1; e < NEXP; ++e) if (acc[e] > m0) { m0 = acc[e]; i0 = e; }
        int i1 = -1; float m1 = -3.0e38f;
        for (int e = 0; e < NEXP; ++e) if (e != i0 && acc[e] > m1) { m1 = acc[e]; i1 = e; }
        float d  = __expf(m1 - m0);
        float w0 = 1.f / (1.f + d);
        topk_idx[n * 2 + 0] = i0;
        topk_idx[n * 2 + 1] = i1;
        topk_w [n * 2 + 0] = w0;
        topk_w [n * 2 + 1] = 1.f - w0;
    }
}

// ---------------------------------------------------------------------------
// Counting-sort permutation + per-XCD work queues (PARALLEL queue build).
// Queue entry: e | (rowTile<<4) | (colTile<<9); -1 = empty.
// Col-major order so concurrently-running blocks in an XCD share a B-panel
// (B stays in the XCD's L2; A panel also L2-resident).
__global__ __launch_bounds__(256) void k_build_perm(
    const int* __restrict__ topk_idx, const float* __restrict__ topk_w,
    int* __restrict__ offsets, int* __restrict__ perm_slot, float* __restrict__ row_w,
    int* __restrict__ q1, int* __restrict__ q2)
{
    __shared__ int cnt[NEXP];
    __shared__ int cur[NEXP];
    __shared__ int off[NEXP + 1];
    const int t = threadIdx.x;
    if (t < NEXP) cnt[t] = 0;
    __syncthreads();
    for (int s = t; s < NKROWS; s += 256) atomicAdd(&cnt[topk_idx[s]], 1);
    __syncthreads();
    if (t == 0) {
        int a = 0;
        for (int e = 0; e < NEXP; ++e) { off[e] = a; a += cnt[e]; cur[e] = off[e]; }
        off[NEXP] = a;
    }
    __syncthreads();
    // parallel queue build (each slot independent)
    for (int i = t; i < NEXP * Q1LEN; i += 256) {
        int e = i >> 8;                    // Q1LEN = 256
        int j = i & (Q1LEN - 1);
        int rts = (cnt[e] + 127) >> 7;
        int v = -1;
        if (j < 16 * rts) { int col = j / rts; int r = j - col * rts; v = e | (r << 4) | (col << 9); }
        q1[i] = v;
    }
    for (int i = t; i < NEXP * Q2LEN; i += 256) {
        int e = i >> 7;                    // Q2LEN = 128
        int j = i & (Q2LEN - 1);
        int rts = (cnt[e] + 127) >> 7;
        int v = -1;
        if (j < 8 * rts) { int col = j / rts; int r = j - col * rts; v = e | (r << 4) | (col << 9); }
        q2[i] = v;
    }
    for (int s = t; s < NKROWS; s += 256) {
        int e = topk_idx[s];
        int pos = atomicAdd(&cur[e], 1);
        perm_slot[pos] = s;
        row_w[pos] = topk_w[s];
    }
    if (t < NEXP + 1) offsets[t] = off[t];
}

// ---------------------------------------------------------------------------
// GEMM1: act[p][f] = silu(gate)*up. Block 128 rows x 64 f-cols (gate AND up).
// 4 waves (2x2). 2-deep DMA prefetch, counted vmcnt(8), raw barriers.
__global__ __launch_bounds__(256, 2) void k_gemm1(
    const unsigned short* __restrict__ hbf, const unsigned short* __restrict__ gubf,
    const int* __restrict__ offsets, const int* __restrict__ perm_slot,
    const int* __restrict__ q1,
    unsigned short* __restrict__ act)
{
    const int bid = blockIdx.x;
    const int q = q1[(bid & 7) * Q1LEN + (bid >> 3)];   // XCD-local queue
    if (q < 0) return;
    const int e  = q & 15;
    const int rt = (q >> 4) & 31;
    const int c0 = (q >> 9) * 64;
    const int off_e = offsets[e];
    const int n_e   = offsets[e + 1] - off_e;
    const int p0 = off_e + rt * 128;
    const int nr = min(128, n_e - rt * 128);

    __shared__ __align__(16) char smA [2][128 * 128];   // bf16 128r x 64K
    __shared__ __align__(16) char smBg[2][64 * 128];
    __shared__ __align__(16) char smBu[2][64 * 128];
    __shared__ int sTok[128];

    const int t = threadIdx.x;
    const int lane = t & 63;
    const int wv = t >> 6;
    const int wr = wv >> 1, wc = wv & 1;
    if (t < 128) sTok[t] = perm_slot[min(p0 + t, NKROWS - 1)] >> 1;
    __syncthreads();

    const int rin = lane >> 3;
    const int pre = ((lane & 7) << 4) ^ (rin << 4);   // pre-swizzled source byte

    const char* asrc[4];
    int aldo[4];
#pragma unroll
    for (int c = 0; c < 4; ++c) {
        int ch = wv * 4 + c;
        int row = ch * 8 + rin;
        asrc[c] = (const char*)(hbf + (size_t)sTok[row] * HDIM) + pre;
        aldo[c] = ch * 1024;
    }
    const unsigned short* guE = gubf + (size_t)e * (2 * FDIM) * HDIM;
    const char* gsrc[2];
    const char* usrc[2];
    int bldo[2];
#pragma unroll
    for (int c = 0; c < 2; ++c) {
        int ch = wv * 2 + c;
        int col = ch * 8 + rin;
        gsrc[c] = (const char*)(guE + (size_t)(c0 + col) * HDIM) + pre;
        usrc[c] = (const char*)(guE + (size_t)(FDIM + c0 + col) * HDIM) + pre;
        bldo[c] = ch * 1024;
    }

    floatx4 accg[4][2], accu[4][2];
#pragma unroll
    for (int m = 0; m < 4; ++m)
#pragma unroll
        for (int nn = 0; nn < 2; ++nn) { accg[m][nn] = (floatx4)0.f; accu[m][nn] = (floatx4)0.f; }

#define STAGE1(k0, buf)                                                         \
    {                                                                           \
        _Pragma("unroll")                                                       \
        for (int c = 0; c < 4; ++c) dma16(asrc[c] + (size_t)(k0) * 2, smA [buf] + aldo[c]); \
        _Pragma("unroll")                                                       \
        for (int c = 0; c < 2; ++c) dma16(gsrc[c] + (size_t)(k0) * 2, smBg[buf] + bldo[c]); \
        _Pragma("unroll")                                                       \
        for (int c = 0; c < 2; ++c) dma16(usrc[c] + (size_t)(k0) * 2, smBu[buf] + bldo[c]); \
    }

    STAGE1(0, 0);
    STAGE1(64, 1);

    for (int step = 0; step < 16; ++step) {
        if (step < 15) asm volatile("s_waitcnt vmcnt(8)" ::: "memory");
        else           asm volatile("s_waitcnt vmcnt(0)" ::: "memory");
        __builtin_amdgcn_s_barrier();
        __builtin_amdgcn_sched_barrier(0);
        const int cur = step & 1;
#pragma unroll
        for (int kk = 0; kk < 2; ++kk) {
            const int kA = kk * 64 + (lane >> 4) * 16;
            bf16x8 a[4], fg[2], fu[2];
#pragma unroll
            for (int m = 0; m < 4; ++m) {
                int row = wr * 64 + m * 16 + (lane & 15);
                a[m] = *reinterpret_cast<const bf16x8*>(&smA[cur][row * 128 + (kA ^ ((row & 7) << 4))]);
            }
#pragma unroll
            for (int nn = 0; nn < 2; ++nn) {
                int cc = wc * 32 + nn * 16 + (lane & 15);
                int ad = cc * 128 + (kA ^ ((cc & 7) << 4));
                fg[nn] = *reinterpret_cast<const bf16x8*>(&smBg[cur][ad]);
                fu[nn] = *reinterpret_cast<const bf16x8*>(&smBu[cur][ad]);
            }
#pragma unroll
            for (int m = 0; m < 4; ++m)
#pragma unroll
                for (int nn = 0; nn < 2; ++nn) {
                    accg[m][nn] = __builtin_amdgcn_mfma_f32_16x16x32_bf16(a[m], fg[nn], accg[m][nn], 0, 0, 0);
                    accu[m][nn] = __builtin_amdgcn_mfma_f32_16x16x32_bf16(a[m], fu[nn], accu[m][nn], 0, 0, 0);
                }
        }
        __builtin_amdgcn_sched_barrier(0);
        __builtin_amdgcn_s_barrier();            // all waves done reading buf cur
        if (step < 14) STAGE1((step + 2) * 64, cur);
    }
#undef STAGE1

    // epilogue: silu(gate) * up -> act (bf16)
#pragma unroll
    for (int m = 0; m < 4; ++m)
#pragma unroll
        for (int nn = 0; nn < 2; ++nn)
#pragma unroll
            for (int j = 0; j < 4; ++j) {
                int rr = wr * 64 + m * 16 + ((lane >> 4) << 2) + j;
                if (rr < nr) {
                    int f = c0 + wc * 32 + nn * 16 + (lane & 15);
                    float gg = accg[m][nn][j];
                    float uu = accu[m][nn][j];
                    float s = gg / (1.f + __expf(-gg));
                    act[(size_t)(p0 + rr) * FDIM + f] = f2bf(s * uu);
                }
            }
}

// ---------------------------------------------------------------------------
// GEMM2: partial[slot][h] = w * (act_row . dp[e][h][:]), bf16 out.
// Block 128 rows x 128 h-cols; 4 waves (2x2), wave 64x64, acc[4][4].
__global__ __launch_bounds__(256, 2) void k_gemm2(
    const unsigned short* __restrict__ act, const unsigned short* __restrict__ dpbf,
    const int* __restrict__ offsets, const int* __restrict__ perm_slot,
    const int* __restrict__ q2,
    const float* __restrict__ row_w, unsigned short* __restrict__ partial)
{
    const int bid = blockIdx.x;
    const int q = q2[(bid & 7) * Q2LEN + (bid >> 3)];   // XCD-local queue
    if (q < 0) return;
    const int e  = q & 15;
    const int rt = (q >> 4) & 31;
    const int c0 = (q >> 9) * 128;
    const int off_e = offsets[e];
    const int n_e   = offsets[e + 1] - off_e;
    const int p0 = off_e + rt * 128;
    const int nr = min(128, n_e - rt * 128);

    __shared__ __align__(16) char smA[2][128 * 128];
    __shared__ __align__(16) char smB[2][128 * 128];
    __shared__ int   sSlot[128];
    __shared__ float sW[128];

    const int t = threadIdx.x;
    const int lane = t & 63;
    const int wv = t >> 6;
    const int wr = wv >> 1, wc = wv & 1;
    if (t < 128) {
        int p = min(p0 + t, NKROWS - 1);
        sSlot[t] = perm_slot[p];
        sW[t]    = row_w[p];
    }
    __syncthreads();

    const int rin = lane >> 3;
    const int pre = ((lane & 7) << 4) ^ (rin << 4);

    const char* asrc[4];
    int aldo[4];
#pragma unroll
    for (int c = 0; c < 4; ++c) {
        int ch = wv * 4 + c;
        int row = ch * 8 + rin;
        int p = min(p0 + row, NKROWS - 1);
        asrc[c] = (const char*)(act + (size_t)p * FDIM) + pre;
        aldo[c] = ch * 1024;
    }
    const unsigned short* dpE = dpbf + (size_t)e * HDIM * FDIM;
    const char* bsrc[4];
    int bldo[4];
#pragma unroll
    for (int c = 0; c < 4; ++c) {
        int ch = wv * 4 + c;
        int col = ch * 8 + rin;
        bsrc[c] = (const char*)(dpE + (size_t)(c0 + col) * FDIM) + pre;
        bldo[c] = ch * 1024;
    }

    floatx4 acc[4][4];
#pragma unroll
    for (int m = 0; m < 4; ++m)
#pragma unroll
        for (int nn = 0; nn < 4; ++nn) acc[m][nn] = (floatx4)0.f;

#define STAGE2(k0, buf)                                                         \
    {                                                                           \
        _Pragma("unroll")                                                       \
        for (int c = 0; c < 4; ++c) dma16(asrc[c] + (size_t)(k0) * 2, smA[buf] + aldo[c]); \
        _Pragma("unroll")                                                       \
        for (int c = 0; c < 4; ++c) dma16(bsrc[c] + (size_t)(k0) * 2, smB[buf] + bldo[c]); \
    }

    STAGE2(0, 0);
    STAGE2(64, 1);

    for (int step = 0; step < 16; ++step) {
        if (step < 15) asm volatile("s_waitcnt vmcnt(8)" ::: "memory");
        else           asm volatile("s_waitcnt vmcnt(0)" ::: "memory");
        __builtin_amdgcn_s_barrier();
        __builtin_amdgcn_sched_barrier(0);
        const int cur = step & 1;
#pragma unroll
        for (int kk = 0; kk < 2; ++kk) {
            const int kA = kk * 64 + (lane >> 4) * 16;
            bf16x8 a[4], fb[4];
#pragma unroll
            for (int m = 0; m < 4; ++m) {
                int row = wr * 64 + m * 16 + (lane & 15);
                a[m] = *reinterpret_cast<const bf16x8*>(&smA[cur][row * 128 + (kA ^ ((row & 7) << 4))]);
            }
#pragma unroll
            for (int nn = 0; nn < 4; ++nn) {
                int cc = wc * 64 + nn * 16 + (lane & 15);
                fb[nn] = *reinterpret_cast<const bf16x8*>(&smB[cur][cc * 128 + (kA ^ ((cc & 7) << 4))]);
            }
#pragma unroll
            for (int m = 0; m < 4; ++m)
#pragma unroll
                for (int nn = 0; nn < 4; ++nn)
                    acc[m][nn] = __builtin_amdgcn_mfma_f32_16x16x32_bf16(a[m], fb[nn], acc[m][nn], 0, 0, 0);
        }
        __builtin_amdgcn_sched_barrier(0);
        __builtin_amdgcn_s_barrier();
        if (step < 14) STAGE2((step + 2) * 64, cur);
    }
#undef STAGE2

#pragma unroll
    for (int m = 0; m < 4; ++m)
#pragma unroll
        for (int nn = 0; nn < 4; ++nn)
#pragma unroll
            for (int j = 0; j < 4; ++j) {
                int rr = wr * 64 + m * 16 + ((lane >> 4) << 2) + j;
                if (rr < nr) {
                    int hcol = c0 + wc * 64 + nn * 16 + (lane & 15);
                    partial[(size_t)sSlot[rr] * HDIM + hcol] = f2bf(sW[rr] * acc[m][nn][j]);
                }
            }
}

// ---------------------------------------------------------------------------
// out[n][h] = partial[2n][h] + partial[2n+1][h]  (bf16 -> fp32)
__global__ __launch_bounds__(256) void k_combine(
    const unsigned short* __restrict__ partial, float* __restrict__ out)
{
    int gid = blockIdx.x * 256 + threadIdx.x;   // NTOK * H / 8 = 262144
    int n = gid >> 7;
    int r = gid & 127;
    uint4 a = reinterpret_cast<const uint4*>(partial + (size_t)(2 * n) * HDIM)[r];
    uint4 b = reinterpret_cast<const uint4*>(partial + (size_t)(2 * n + 1) * HDIM)[r];
    float4 o0, o1;
    o0.x = bf2f(a.x & 0xFFFF) + bf2f(b.x & 0xFFFF);
    o0.y = bf2f(a.x >> 16)    + bf2f(b.x >> 16);
    o0.z = bf2f(a.y & 0xFFFF) + bf2f(b.y & 0xFFFF);
    o0.w = bf2f(a.y >> 16)    + bf2f(b.y >> 16);
    o1.x = bf2f(a.z & 0xFFFF) + bf2f(b.z & 0xFFFF);
    o1.y = bf2f(a.z >> 16)    + bf2f(b.z >> 16);
    o1.z = bf2f(a.w & 0xFFFF) + bf2f(b.w & 0xFFFF);
    o1.w = bf2f(a.w >> 16)    + bf2f(b.w >> 16);
    float4* op = reinterpret_cast<float4*>(out + (size_t)n * HDIM + r * 8);
    op[0] = o0;
    op[1] = o1;
}

// ---------------------------------------------------------------------------
extern "C" void kernel_launch(void* const* d_in, const int* in_sizes, int n_in,
                              void* d_out, int out_size, void* d_ws, size_t ws_size,
                              hipStream_t stream)
{
    const float* h  = (const float*)d_in[0];
    const float* rw = (const float*)d_in[1];
    const float* gu = (const float*)d_in[2];
    const float* dp = (const float*)d_in[3];
    float* out = (float*)d_out;

    char* ws = (char*)d_ws;
    int*            topk_idx  = (int*)   (ws + 0);
    float*          topk_w    = (float*) (ws + 16384);
    int*            offsets   = (int*)   (ws + 32768);
    int*            perm_slot = (int*)   (ws + 36864);
    float*          row_w     = (float*) (ws + 53248);
    int*            q1        = (int*)   (ws + 69632);   // 8*256*4 = 8192 B
    int*            q2        = (int*)   (ws + 77824);   // 8*128*4 = 4096 B
    unsigned short* hbf       = (unsigned short*)(ws + (1u  << 20));  // 8MB
    unsigned short* partial   = (unsigned short*)(ws + (1u  << 20));  // overlays hbf (dead after gemm1)
    unsigned short* act       = (unsigned short*)(ws + (9u  << 20));  // 8MB
    unsigned short* gubf      = (unsigned short*)(ws + (17u << 20));  // 32MB
    unsigned short* dpbf      = (unsigned short*)(ws + (49u << 20));  // 16MB

    hipLaunchKernelGGL(k_pre,        dim3(12800),       dim3(256), 0, stream, gu, gubf, dp, dpbf, h, rw, hbf, topk_idx, topk_w);
    hipLaunchKernelGGL(k_build_perm, dim3(1),           dim3(256), 0, stream, topk_idx, topk_w, offsets, perm_slot, row_w, q1, q2);
    hipLaunchKernelGGL(k_gemm1,      dim3(8 * Q1LEN),   dim3(256), 0, stream, hbf, gubf, offsets, perm_slot, q1, act);
    hipLaunchKernelGGL(k_gemm2,      dim3(8 * Q2LEN),   dim3(256), 0, stream, act, dpbf, offsets, perm_slot, q2, row_w, partial);
    hipLaunchKernelGGL(k_combine,    dim3(1024),        dim3(256), 0, stream, partial, out);
}

// Round 9
// 100.532 us; speedup vs baseline: 1.5753x; 1.0705x over previous
//
#include <hip/hip_runtime.h>

// ---------------------------------------------------------------------------
// FakeFusedMoE: E=8, H=1024, F=1024, top-2, N=2048 tokens (4096 routed rows).
// Sparse grouped-GEMM MoE, bf16 MFMA.
//   k_pre       : grid-stride fp32->bf16 convert (gu,dp) ++ router+hidden cvt
//   k_build_perm: counting-sort + per-XCD work queues (parallel build)
//   k_gemm1/2   : SINGLE-BUFFER all-bf16-DMA GEMMs at 4 blocks/CU
//                 (m97/m114 mechanism: cross-block overlap hides the per-step
//                 vmcnt drain; beats counted-vmcnt dbuf at 2 blocks/CU)
//   k_combine   : out[n] = partial[2n] + partial[2n+1]
// ---------------------------------------------------------------------------

#define NTOK   2048
#define HDIM   1024
#define FDIM   1024
#define NEXP   8
#define NKROWS 4096
#define Q1LEN  256    // per-XCD gemm1 queue (16 cols x up to 16 row tiles)
#define Q2LEN  128    // per-XCD gemm2 queue (8 cols x up to 16 row tiles)

typedef __attribute__((ext_vector_type(8))) __bf16 bf16x8;
typedef __attribute__((ext_vector_type(4))) float  floatx4;

__device__ __forceinline__ unsigned short f2bf(float x) {
    unsigned int u = __builtin_bit_cast(unsigned int, x);
    u += 0x7FFFu + ((u >> 16) & 1u);
    return (unsigned short)(u >> 16);
}

__device__ __forceinline__ float bf2f(unsigned short v) {
    unsigned int u = (unsigned int)v << 16;
    return __builtin_bit_cast(float, u);
}

__device__ __forceinline__ uint4 pack8(float4 a, float4 b) {
    uint4 o;
    o.x = (unsigned)f2bf(a.x) | ((unsigned)f2bf(a.y) << 16);
    o.y = (unsigned)f2bf(a.z) | ((unsigned)f2bf(a.w) << 16);
    o.z = (unsigned)f2bf(b.x) | ((unsigned)f2bf(b.y) << 16);
    o.w = (unsigned)f2bf(b.z) | ((unsigned)f2bf(b.w) << 16);
    return o;
}

// async global->LDS, 16B/lane; LDS dest = wave-uniform base + lane*16
__device__ __forceinline__ void dma16(const void* g, void* l) {
    __builtin_amdgcn_global_load_lds(
        (const __attribute__((address_space(1))) unsigned int*)g,
        (__attribute__((address_space(3))) unsigned int*)l, 16, 0, 0);
}

// ---------------------------------------------------------------------------
// Fused pre-pass:
//   blocks [0,2048)    : grid-stride fp32->bf16 convert of gu then dp
//                        (6 virtual blocks each; avoids the 12800-tiny-block
//                        dispatch-latency wall seen in R7: 43us @ 3.5TB/s)
//   blocks [2048,2560) : router, one wave per token
__global__ __launch_bounds__(256) void k_pre(
    const float* __restrict__ gu, unsigned short* __restrict__ gubf,
    const float* __restrict__ dp, unsigned short* __restrict__ dpbf,
    const float* __restrict__ h, const float* __restrict__ rw,
    unsigned short* __restrict__ hbf,
    int* __restrict__ topk_idx, float* __restrict__ topk_w)
{
    const int b = blockIdx.x;
    if (b < 2048) {
        for (int vb = b; vb < 12288; vb += 2048) {
            const float* src;
            unsigned short* dst;
            size_t base;
            if (vb < 8192) { base = (size_t)vb * 2048;          src = gu; dst = gubf; }
            else           { base = (size_t)(vb - 8192) * 2048; src = dp; dst = dpbf; }
            size_t i = base + (size_t)threadIdx.x * 8;
            const float4* s = reinterpret_cast<const float4*>(src + i);
            float4 a = s[0], c = s[1];
            *reinterpret_cast<uint4*>(dst + i) = pack8(a, c);
        }
        return;
    }
    // ---- router
    const int lane = threadIdx.x & 63;
    const int wave = threadIdx.x >> 6;
    const int n = (b - 2048) * 4 + wave;

    const float4* hp = reinterpret_cast<const float4*>(h + (size_t)n * HDIM);
    uint2* hb = reinterpret_cast<uint2*>(hbf + (size_t)n * HDIM);
    float acc[NEXP];
#pragma unroll
    for (int e = 0; e < NEXP; ++e) acc[e] = 0.f;

#pragma unroll
    for (int i0 = 0; i0 < HDIM / 4; i0 += 64) {
        float4 hv = hp[i0 + lane];
        uint2 o;
        o.x = (unsigned)f2bf(hv.x) | ((unsigned)f2bf(hv.y) << 16);
        o.y = (unsigned)f2bf(hv.z) | ((unsigned)f2bf(hv.w) << 16);
        hb[i0 + lane] = o;
#pragma unroll
        for (int e = 0; e < NEXP; ++e) {
            float4 rv = reinterpret_cast<const float4*>(rw + e * HDIM)[i0 + lane];
            acc[e] += hv.x * rv.x + hv.y * rv.y + hv.z * rv.z + hv.w * rv.w;
        }
    }
#pragma unroll
    for (int e = 0; e < NEXP; ++e) {
#pragma unroll
        for (int off = 32; off > 0; off >>= 1)
            acc[e] += __shfl_xor(acc[e], off);
    }
    if (lane == 0) {
        int i0 = 0; float m0 = acc[0];
        for (int e = 1; e < NEXP; ++e) if (acc[e] > m0) { m0 = acc[e]; i0 = e; }
        int i1 = -1; float m1 = -3.0e38f;
        for (int e = 0; e < NEXP; ++e) if (e != i0 && acc[e] > m1) { m1 = acc[e]; i1 = e; }
        float d  = __expf(m1 - m0);
        float w0 = 1.f / (1.f + d);
        topk_idx[n * 2 + 0] = i0;
        topk_idx[n * 2 + 1] = i1;
        topk_w [n * 2 + 0] = w0;
        topk_w [n * 2 + 1] = 1.f - w0;
    }
}

// ---------------------------------------------------------------------------
// Counting-sort permutation + per-XCD work queues (parallel build).
// Queue entry: e | (rowTile<<4) | (colTile<<9); -1 = empty.
__global__ __launch_bounds__(256) void k_build_perm(
    const int* __restrict__ topk_idx, const float* __restrict__ topk_w,
    int* __restrict__ offsets, int* __restrict__ perm_slot, float* __restrict__ row_w,
    int* __restrict__ q1, int* __restrict__ q2)
{
    __shared__ int cnt[NEXP];
    __shared__ int cur[NEXP];
    __shared__ int off[NEXP + 1];
    const int t = threadIdx.x;
    if (t < NEXP) cnt[t] = 0;
    __syncthreads();
    for (int s = t; s < NKROWS; s += 256) atomicAdd(&cnt[topk_idx[s]], 1);
    __syncthreads();
    if (t == 0) {
        int a = 0;
        for (int e = 0; e < NEXP; ++e) { off[e] = a; a += cnt[e]; cur[e] = off[e]; }
        off[NEXP] = a;
    }
    __syncthreads();
    for (int i = t; i < NEXP * Q1LEN; i += 256) {
        int e = i >> 8;                    // Q1LEN = 256
        int j = i & (Q1LEN - 1);
        int rts = (cnt[e] + 127) >> 7;
        int v = -1;
        if (j < 16 * rts) { int col = j / rts; int r = j - col * rts; v = e | (r << 4) | (col << 9); }
        q1[i] = v;
    }
    for (int i = t; i < NEXP * Q2LEN; i += 256) {
        int e = i >> 7;                    // Q2LEN = 128
        int j = i & (Q2LEN - 1);
        int rts = (cnt[e] + 127) >> 7;
        int v = -1;
        if (j < 8 * rts) { int col = j / rts; int r = j - col * rts; v = e | (r << 4) | (col << 9); }
        q2[i] = v;
    }
    for (int s = t; s < NKROWS; s += 256) {
        int e = topk_idx[s];
        int pos = atomicAdd(&cur[e], 1);
        perm_slot[pos] = s;
        row_w[pos] = topk_w[s];
    }
    if (t < NEXP + 1) offsets[t] = off[t];
}

// ---------------------------------------------------------------------------
// GEMM1: act[p][f] = silu(gate)*up. Block 128 rows x 64 f-cols (gate AND up).
// 4 waves (2x2). SINGLE-buffer LDS (33KB -> 4 blocks/CU), 2 barriers/step,
// all operands bf16 via global_load_lds with pre-swizzled source.
__global__ __launch_bounds__(256, 4) void k_gemm1(
    const unsigned short* __restrict__ hbf, const unsigned short* __restrict__ gubf,
    const int* __restrict__ offsets, const int* __restrict__ perm_slot,
    const int* __restrict__ q1,
    unsigned short* __restrict__ act)
{
    const int bid = blockIdx.x;
    const int q = q1[(bid & 7) * Q1LEN + (bid >> 3)];   // XCD-local queue
    if (q < 0) return;
    const int e  = q & 15;
    const int rt = (q >> 4) & 31;
    const int c0 = (q >> 9) * 64;
    const int off_e = offsets[e];
    const int n_e   = offsets[e + 1] - off_e;
    const int p0 = off_e + rt * 128;
    const int nr = min(128, n_e - rt * 128);

    __shared__ __align__(16) char smA [128 * 128];   // bf16 128r x 64K
    __shared__ __align__(16) char smBg[64 * 128];
    __shared__ __align__(16) char smBu[64 * 128];
    __shared__ int sTok[128];

    const int t = threadIdx.x;
    const int lane = t & 63;
    const int wv = t >> 6;
    const int wr = wv >> 1, wc = wv & 1;
    if (t < 128) sTok[t] = perm_slot[min(p0 + t, NKROWS - 1)] >> 1;
    __syncthreads();

    const int rin = lane >> 3;
    const int pre = ((lane & 7) << 4) ^ (rin << 4);   // pre-swizzled source byte

    const char* asrc[4];
    int aldo[4];
#pragma unroll
    for (int c = 0; c < 4; ++c) {
        int ch = wv * 4 + c;
        int row = ch * 8 + rin;
        asrc[c] = (const char*)(hbf + (size_t)sTok[row] * HDIM) + pre;
        aldo[c] = ch * 1024;
    }
    const unsigned short* guE = gubf + (size_t)e * (2 * FDIM) * HDIM;
    const char* gsrc[2];
    const char* usrc[2];
    int bldo[2];
#pragma unroll
    for (int c = 0; c < 2; ++c) {
        int ch = wv * 2 + c;
        int col = ch * 8 + rin;
        gsrc[c] = (const char*)(guE + (size_t)(c0 + col) * HDIM) + pre;
        usrc[c] = (const char*)(guE + (size_t)(FDIM + c0 + col) * HDIM) + pre;
        bldo[c] = ch * 1024;
    }

    floatx4 accg[4][2], accu[4][2];
#pragma unroll
    for (int m = 0; m < 4; ++m)
#pragma unroll
        for (int nn = 0; nn < 2; ++nn) { accg[m][nn] = (floatx4)0.f; accu[m][nn] = (floatx4)0.f; }

    for (int k0 = 0; k0 < HDIM; k0 += 64) {
        if (k0) __syncthreads();             // readers done before overwrite
#pragma unroll
        for (int c = 0; c < 4; ++c) dma16(asrc[c] + (size_t)k0 * 2, smA  + aldo[c]);
#pragma unroll
        for (int c = 0; c < 2; ++c) dma16(gsrc[c] + (size_t)k0 * 2, smBg + bldo[c]);
#pragma unroll
        for (int c = 0; c < 2; ++c) dma16(usrc[c] + (size_t)k0 * 2, smBu + bldo[c]);
        __syncthreads();                     // vmcnt(0) drain -> data visible
#pragma unroll
        for (int kk = 0; kk < 2; ++kk) {
            const int kA = kk * 64 + (lane >> 4) * 16;
            bf16x8 a[4], fg[2], fu[2];
#pragma unroll
            for (int m = 0; m < 4; ++m) {
                int row = wr * 64 + m * 16 + (lane & 15);
                a[m] = *reinterpret_cast<const bf16x8*>(smA + row * 128 + (kA ^ ((row & 7) << 4)));
            }
#pragma unroll
            for (int nn = 0; nn < 2; ++nn) {
                int cc = wc * 32 + nn * 16 + (lane & 15);
                int ad = cc * 128 + (kA ^ ((cc & 7) << 4));
                fg[nn] = *reinterpret_cast<const bf16x8*>(smBg + ad);
                fu[nn] = *reinterpret_cast<const bf16x8*>(smBu + ad);
            }
#pragma unroll
            for (int m = 0; m < 4; ++m)
#pragma unroll
                for (int nn = 0; nn < 2; ++nn) {
                    accg[m][nn] = __builtin_amdgcn_mfma_f32_16x16x32_bf16(a[m], fg[nn], accg[m][nn], 0, 0, 0);
                    accu[m][nn] = __builtin_amdgcn_mfma_f32_16x16x32_bf16(a[m], fu[nn], accu[m][nn], 0, 0, 0);
                }
        }
    }

    // epilogue: silu(gate) * up -> act (bf16)
#pragma unroll
    for (int m = 0; m < 4; ++m)
#pragma unroll
        for (int nn = 0; nn < 2; ++nn)
#pragma unroll
            for (int j = 0; j < 4; ++j) {
                int rr = wr * 64 + m * 16 + ((lane >> 4) << 2) + j;
                if (rr < nr) {
                    int f = c0 + wc * 32 + nn * 16 + (lane & 15);
                    float gg = accg[m][nn][j];
                    float uu = accu[m][nn][j];
                    float s = gg / (1.f + __expf(-gg));
                    act[(size_t)(p0 + rr) * FDIM + f] = f2bf(s * uu);
                }
            }
}

// ---------------------------------------------------------------------------
// GEMM2: partial[slot][h] = w * (act_row . dp[e][h][:]), bf16 out.
// Block 128 rows x 128 h-cols; 4 waves (2x2), wave 64x64, acc[4][4].
// Single-buffer LDS (33KB -> 4 blocks/CU).
__global__ __launch_bounds__(256, 4) void k_gemm2(
    const unsigned short* __restrict__ act, const unsigned short* __restrict__ dpbf,
    const int* __restrict__ offsets, const int* __restrict__ perm_slot,
    const int* __restrict__ q2,
    const float* __restrict__ row_w, unsigned short* __restrict__ partial)
{
    const int bid = blockIdx.x;
    const int q = q2[(bid & 7) * Q2LEN + (bid >> 3)];   // XCD-local queue
    if (q < 0) return;
    const int e  = q & 15;
    const int rt = (q >> 4) & 31;
    const int c0 = (q >> 9) * 128;
    const int off_e = offsets[e];
    const int n_e   = offsets[e + 1] - off_e;
    const int p0 = off_e + rt * 128;
    const int nr = min(128, n_e - rt * 128);

    __shared__ __align__(16) char smA[128 * 128];
    __shared__ __align__(16) char smB[128 * 128];
    __shared__ int   sSlot[128];
    __shared__ float sW[128];

    const int t = threadIdx.x;
    const int lane = t & 63;
    const int wv = t >> 6;
    const int wr = wv >> 1, wc = wv & 1;
    if (t < 128) {
        int p = min(p0 + t, NKROWS - 1);
        sSlot[t] = perm_slot[p];
        sW[t]    = row_w[p];
    }
    __syncthreads();

    const int rin = lane >> 3;
    const int pre = ((lane & 7) << 4) ^ (rin << 4);

    const char* asrc[4];
    int aldo[4];
#pragma unroll
    for (int c = 0; c < 4; ++c) {
        int ch = wv * 4 + c;
        int row = ch * 8 + rin;
        int p = min(p0 + row, NKROWS - 1);
        asrc[c] = (const char*)(act + (size_t)p * FDIM) + pre;
        aldo[c] = ch * 1024;
    }
    const unsigned short* dpE = dpbf + (size_t)e * HDIM * FDIM;
    const char* bsrc[4];
    int bldo[4];
#pragma unroll
    for (int c = 0; c < 4; ++c) {
        int ch = wv * 4 + c;
        int col = ch * 8 + rin;
        bsrc[c] = (const char*)(dpE + (size_t)(c0 + col) * FDIM) + pre;
        bldo[c] = ch * 1024;
    }

    floatx4 acc[4][4];
#pragma unroll
    for (int m = 0; m < 4; ++m)
#pragma unroll
        for (int nn = 0; nn < 4; ++nn) acc[m][nn] = (floatx4)0.f;

    for (int k0 = 0; k0 < FDIM; k0 += 64) {
        if (k0) __syncthreads();
#pragma unroll
        for (int c = 0; c < 4; ++c) dma16(asrc[c] + (size_t)k0 * 2, smA + aldo[c]);
#pragma unroll
        for (int c = 0; c < 4; ++c) dma16(bsrc[c] + (size_t)k0 * 2, smB + bldo[c]);
        __syncthreads();
#pragma unroll
        for (int kk = 0; kk < 2; ++kk) {
            const int kA = kk * 64 + (lane >> 4) * 16;
            bf16x8 a[4], fb[4];
#pragma unroll
            for (int m = 0; m < 4; ++m) {
                int row = wr * 64 + m * 16 + (lane & 15);
                a[m] = *reinterpret_cast<const bf16x8*>(smA + row * 128 + (kA ^ ((row & 7) << 4)));
            }
#pragma unroll
            for (int nn = 0; nn < 4; ++nn) {
                int cc = wc * 64 + nn * 16 + (lane & 15);
                fb[nn] = *reinterpret_cast<const bf16x8*>(smB + cc * 128 + (kA ^ ((cc & 7) << 4)));
            }
#pragma unroll
            for (int m = 0; m < 4; ++m)
#pragma unroll
                for (int nn = 0; nn < 4; ++nn)
                    acc[m][nn] = __builtin_amdgcn_mfma_f32_16x16x32_bf16(a[m], fb[nn], acc[m][nn], 0, 0, 0);
        }
    }

#pragma unroll
    for (int m = 0; m < 4; ++m)
#pragma unroll
        for (int nn = 0; nn < 4; ++nn)
#pragma unroll
            for (int j = 0; j < 4; ++j) {
                int rr = wr * 64 + m * 16 + ((lane >> 4) << 2) + j;
                if (rr < nr) {
                    int hcol = c0 + wc * 64 + nn * 16 + (lane & 15);
                    partial[(size_t)sSlot[rr] * HDIM + hcol] = f2bf(sW[rr] * acc[m][nn][j]);
                }
            }
}

// ---------------------------------------------------------------------------
// out[n][h] = partial[2n][h] + partial[2n+1][h]  (bf16 -> fp32)
__global__ __launch_bounds__(256) void k_combine(
    const unsigned short* __restrict__ partial, float* __restrict__ out)
{
    int gid = blockIdx.x * 256 + threadIdx.x;   // NTOK * H / 8 = 262144
    int n = gid >> 7;
    int r = gid & 127;
    uint4 a = reinterpret_cast<const uint4*>(partial + (size_t)(2 * n) * HDIM)[r];
    uint4 b = reinterpret_cast<const uint4*>(partial + (size_t)(2 * n + 1) * HDIM)[r];
    float4 o0, o1;
    o0.x = bf2f(a.x & 0xFFFF) + bf2f(b.x & 0xFFFF);
    o0.y = bf2f(a.x >> 16)    + bf2f(b.x >> 16);
    o0.z = bf2f(a.y & 0xFFFF) + bf2f(b.y & 0xFFFF);
    o0.w = bf2f(a.y >> 16)    + bf2f(b.y >> 16);
    o1.x = bf2f(a.z & 0xFFFF) + bf2f(b.z & 0xFFFF);
    o1.y = bf2f(a.z >> 16)    + bf2f(b.z >> 16);
    o1.z = bf2f(a.w & 0xFFFF) + bf2f(b.w & 0xFFFF);
    o1.w = bf2f(a.w >> 16)    + bf2f(b.w >> 16);
    float4* op = reinterpret_cast<float4*>(out + (size_t)n * HDIM + r * 8);
    op[0] = o0;
    op[1] = o1;
}

// ---------------------------------------------------------------------------
extern "C" void kernel_launch(void* const* d_in, const int* in_sizes, int n_in,
                              void* d_out, int out_size, void* d_ws, size_t ws_size,
                              hipStream_t stream)
{
    const float* h  = (const float*)d_in[0];
    const float* rw = (const float*)d_in[1];
    const float* gu = (const float*)d_in[2];
    const float* dp = (const float*)d_in[3];
    float* out = (float*)d_out;

    char* ws = (char*)d_ws;
    int*            topk_idx  = (int*)   (ws + 0);
    float*          topk_w    = (float*) (ws + 16384);
    int*            offsets   = (int*)   (ws + 32768);
    int*            perm_slot = (int*)   (ws + 36864);
    float*          row_w     = (float*) (ws + 53248);
    int*            q1        = (int*)   (ws + 69632);   // 8*256*4 = 8192 B
    int*            q2        = (int*)   (ws + 77824);   // 8*128*4 = 4096 B
    unsigned short* hbf       = (unsigned short*)(ws + (1u  << 20));  // 8MB
    unsigned short* partial   = (unsigned short*)(ws + (1u  << 20));  // overlays hbf (dead after gemm1)
    unsigned short* act       = (unsigned short*)(ws + (9u  << 20));  // 8MB
    unsigned short* gubf      = (unsigned short*)(ws + (17u << 20));  // 32MB
    unsigned short* dpbf      = (unsigned short*)(ws + (49u << 20));  // 16MB

    hipLaunchKernelGGL(k_pre,        dim3(2560),      dim3(256), 0, stream, gu, gubf, dp, dpbf, h, rw, hbf, topk_idx, topk_w);
    hipLaunchKernelGGL(k_build_perm, dim3(1),         dim3(256), 0, stream, topk_idx, topk_w, offsets, perm_slot, row_w, q1, q2);
    hipLaunchKernelGGL(k_gemm1,      dim3(8 * Q1LEN), dim3(256), 0, stream, hbf, gubf, offsets, perm_slot, q1, act);
    hipLaunchKernelGGL(k_gemm2,      dim3(8 * Q2LEN), dim3(256), 0, stream, act, dpbf, offsets, perm_slot, q2, row_w, partial);
    hipLaunchKernelGGL(k_combine,    dim3(1024),      dim3(256), 0, stream, partial, out);
}

// Round 10
// 98.466 us; speedup vs baseline: 1.6084x; 1.0210x over previous
//
#include <hip/hip_runtime.h>

// ---------------------------------------------------------------------------
// FakeFusedMoE: E=8, H=1024, F=1024, top-2, N=2048 tokens (4096 routed rows).
// Sparse grouped-GEMM MoE, bf16 MFMA.
//   k_pre       : branch-free batched fp32->bf16 convert (gu: blocks 0-1023,
//                 dp: 1024-1535) ++ router (1536-2047). All loads issued
//                 before any store -> 512B/thread in flight (R9's version was
//                 latency-bound at 44us: data-dependent branch in loop body).
//   k_build_perm: counting-sort + per-XCD work queues (parallel build)
//   k_gemm1/2   : single-buffer all-bf16-DMA GEMMs at 4 blocks/CU (R8-proven)
//   k_combine   : out[n] = partial[2n] + partial[2n+1]
// ---------------------------------------------------------------------------

#define NTOK   2048
#define HDIM   1024
#define FDIM   1024
#define NEXP   8
#define NKROWS 4096
#define Q1LEN  256    // per-XCD gemm1 queue (16 cols x up to 16 row tiles)
#define Q2LEN  128    // per-XCD gemm2 queue (8 cols x up to 16 row tiles)

typedef __attribute__((ext_vector_type(8))) __bf16 bf16x8;
typedef __attribute__((ext_vector_type(4))) float  floatx4;

__device__ __forceinline__ unsigned short f2bf(float x) {
    unsigned int u = __builtin_bit_cast(unsigned int, x);
    u += 0x7FFFu + ((u >> 16) & 1u);
    return (unsigned short)(u >> 16);
}

__device__ __forceinline__ float bf2f(unsigned short v) {
    unsigned int u = (unsigned int)v << 16;
    return __builtin_bit_cast(float, u);
}

__device__ __forceinline__ uint4 pack8(float4 a, float4 b) {
    uint4 o;
    o.x = (unsigned)f2bf(a.x) | ((unsigned)f2bf(a.y) << 16);
    o.y = (unsigned)f2bf(a.z) | ((unsigned)f2bf(a.w) << 16);
    o.z = (unsigned)f2bf(b.x) | ((unsigned)f2bf(b.y) << 16);
    o.w = (unsigned)f2bf(b.z) | ((unsigned)f2bf(b.w) << 16);
    return o;
}

// async global->LDS, 16B/lane; LDS dest = wave-uniform base + lane*16
__device__ __forceinline__ void dma16(const void* g, void* l) {
    __builtin_amdgcn_global_load_lds(
        (const __attribute__((address_space(1))) unsigned int*)g,
        (__attribute__((address_space(3))) unsigned int*)l, 16, 0, 0);
}

// ---------------------------------------------------------------------------
// Branch-free batched fp32->bf16 convert for one 16384-float segment:
// all 16 loads issued before any cvt/store (max memory-level parallelism).
__device__ __forceinline__ void convert_seg(
    const float* __restrict__ src, unsigned short* __restrict__ dst, int tid)
{
    float4 v[16];
#pragma unroll
    for (int it = 0; it < 8; ++it) {
        const float4* s = reinterpret_cast<const float4*>(src + it * 2048 + tid * 8);
        v[2 * it]     = s[0];
        v[2 * it + 1] = s[1];
    }
#pragma unroll
    for (int it = 0; it < 8; ++it)
        *reinterpret_cast<uint4*>(dst + it * 2048 + tid * 8) = pack8(v[2 * it], v[2 * it + 1]);
}

// Fused pre-pass:
//   blocks [0,1024)    : gu fp32->bf16 (16384 floats each, branch-free)
//   blocks [1024,1536) : dp fp32->bf16
//   blocks [1536,2048) : router, one wave per token
__global__ __launch_bounds__(256) void k_pre(
    const float* __restrict__ gu, unsigned short* __restrict__ gubf,
    const float* __restrict__ dp, unsigned short* __restrict__ dpbf,
    const float* __restrict__ h, const float* __restrict__ rw,
    unsigned short* __restrict__ hbf,
    int* __restrict__ topk_idx, float* __restrict__ topk_w)
{
    const int b = blockIdx.x;
    if (b < 1024) {
        convert_seg(gu + (size_t)b * 16384, gubf + (size_t)b * 16384, threadIdx.x);
        return;
    }
    if (b < 1536) {
        size_t base = (size_t)(b - 1024) * 16384;
        convert_seg(dp + base, dpbf + base, threadIdx.x);
        return;
    }
    // ---- router
    const int lane = threadIdx.x & 63;
    const int wave = threadIdx.x >> 6;
    const int n = (b - 1536) * 4 + wave;

    const float4* hp = reinterpret_cast<const float4*>(h + (size_t)n * HDIM);
    uint2* hb = reinterpret_cast<uint2*>(hbf + (size_t)n * HDIM);
    float acc[NEXP];
#pragma unroll
    for (int e = 0; e < NEXP; ++e) acc[e] = 0.f;

#pragma unroll
    for (int i0 = 0; i0 < HDIM / 4; i0 += 64) {
        float4 hv = hp[i0 + lane];
        uint2 o;
        o.x = (unsigned)f2bf(hv.x) | ((unsigned)f2bf(hv.y) << 16);
        o.y = (unsigned)f2bf(hv.z) | ((unsigned)f2bf(hv.w) << 16);
        hb[i0 + lane] = o;
#pragma unroll
        for (int e = 0; e < NEXP; ++e) {
            float4 rv = reinterpret_cast<const float4*>(rw + e * HDIM)[i0 + lane];
            acc[e] += hv.x * rv.x + hv.y * rv.y + hv.z * rv.z + hv.w * rv.w;
        }
    }
#pragma unroll
    for (int e = 0; e < NEXP; ++e) {
#pragma unroll
        for (int off = 32; off > 0; off >>= 1)
            acc[e] += __shfl_xor(acc[e], off);
    }
    if (lane == 0) {
        int i0 = 0; float m0 = acc[0];
        for (int e = 1; e < NEXP; ++e) if (acc[e] > m0) { m0 = acc[e]; i0 = e; }
        int i1 = -1; float m1 = -3.0e38f;
        for (int e = 0; e < NEXP; ++e) if (e != i0 && acc[e] > m1) { m1 = acc[e]; i1 = e; }
        float d  = __expf(m1 - m0);
        float w0 = 1.f / (1.f + d);
        topk_idx[n * 2 + 0] = i0;
        topk_idx[n * 2 + 1] = i1;
        topk_w [n * 2 + 0] = w0;
        topk_w [n * 2 + 1] = 1.f - w0;
    }
}

// ---------------------------------------------------------------------------
// Counting-sort permutation + per-XCD work queues (parallel build).
// Queue entry: e | (rowTile<<4) | (colTile<<9); -1 = empty.
__global__ __launch_bounds__(256) void k_build_perm(
    const int* __restrict__ topk_idx, const float* __restrict__ topk_w,
    int* __restrict__ offsets, int* __restrict__ perm_slot, float* __restrict__ row_w,
    int* __restrict__ q1, int* __restrict__ q2)
{
    __shared__ int cnt[NEXP];
    __shared__ int cur[NEXP];
    __shared__ int off[NEXP + 1];
    const int t = threadIdx.x;
    if (t < NEXP) cnt[t] = 0;
    __syncthreads();
    for (int s = t; s < NKROWS; s += 256) atomicAdd(&cnt[topk_idx[s]], 1);
    __syncthreads();
    if (t == 0) {
        int a = 0;
        for (int e = 0; e < NEXP; ++e) { off[e] = a; a += cnt[e]; cur[e] = off[e]; }
        off[NEXP] = a;
    }
    __syncthreads();
    for (int i = t; i < NEXP * Q1LEN; i += 256) {
        int e = i >> 8;                    // Q1LEN = 256
        int j = i & (Q1LEN - 1);
        int rts = (cnt[e] + 127) >> 7;
        int v = -1;
        if (j < 16 * rts) { int col = j / rts; int r = j - col * rts; v = e | (r << 4) | (col << 9); }
        q1[i] = v;
    }
    for (int i = t; i < NEXP * Q2LEN; i += 256) {
        int e = i >> 7;                    // Q2LEN = 128
        int j = i & (Q2LEN - 1);
        int rts = (cnt[e] + 127) >> 7;
        int v = -1;
        if (j < 8 * rts) { int col = j / rts; int r = j - col * rts; v = e | (r << 4) | (col << 9); }
        q2[i] = v;
    }
    for (int s = t; s < NKROWS; s += 256) {
        int e = topk_idx[s];
        int pos = atomicAdd(&cur[e], 1);
        perm_slot[pos] = s;
        row_w[pos] = topk_w[s];
    }
    if (t < NEXP + 1) offsets[t] = off[t];
}

// ---------------------------------------------------------------------------
// GEMM1: act[p][f] = silu(gate)*up. Block 128 rows x 64 f-cols (gate AND up).
// 4 waves (2x2). SINGLE-buffer LDS (33KB -> 4 blocks/CU), 2 barriers/step,
// all operands bf16 via global_load_lds with pre-swizzled source.
__global__ __launch_bounds__(256, 4) void k_gemm1(
    const unsigned short* __restrict__ hbf, const unsigned short* __restrict__ gubf,
    const int* __restrict__ offsets, const int* __restrict__ perm_slot,
    const int* __restrict__ q1,
    unsigned short* __restrict__ act)
{
    const int bid = blockIdx.x;
    const int q = q1[(bid & 7) * Q1LEN + (bid >> 3)];   // XCD-local queue
    if (q < 0) return;
    const int e  = q & 15;
    const int rt = (q >> 4) & 31;
    const int c0 = (q >> 9) * 64;
    const int off_e = offsets[e];
    const int n_e   = offsets[e + 1] - off_e;
    const int p0 = off_e + rt * 128;
    const int nr = min(128, n_e - rt * 128);

    __shared__ __align__(16) char smA [128 * 128];   // bf16 128r x 64K
    __shared__ __align__(16) char smBg[64 * 128];
    __shared__ __align__(16) char smBu[64 * 128];
    __shared__ int sTok[128];

    const int t = threadIdx.x;
    const int lane = t & 63;
    const int wv = t >> 6;
    const int wr = wv >> 1, wc = wv & 1;
    if (t < 128) sTok[t] = perm_slot[min(p0 + t, NKROWS - 1)] >> 1;
    __syncthreads();

    const int rin = lane >> 3;
    const int pre = ((lane & 7) << 4) ^ (rin << 4);   // pre-swizzled source byte

    const char* asrc[4];
    int aldo[4];
#pragma unroll
    for (int c = 0; c < 4; ++c) {
        int ch = wv * 4 + c;
        int row = ch * 8 + rin;
        asrc[c] = (const char*)(hbf + (size_t)sTok[row] * HDIM) + pre;
        aldo[c] = ch * 1024;
    }
    const unsigned short* guE = gubf + (size_t)e * (2 * FDIM) * HDIM;
    const char* gsrc[2];
    const char* usrc[2];
    int bldo[2];
#pragma unroll
    for (int c = 0; c < 2; ++c) {
        int ch = wv * 2 + c;
        int col = ch * 8 + rin;
        gsrc[c] = (const char*)(guE + (size_t)(c0 + col) * HDIM) + pre;
        usrc[c] = (const char*)(guE + (size_t)(FDIM + c0 + col) * HDIM) + pre;
        bldo[c] = ch * 1024;
    }

    floatx4 accg[4][2], accu[4][2];
#pragma unroll
    for (int m = 0; m < 4; ++m)
#pragma unroll
        for (int nn = 0; nn < 2; ++nn) { accg[m][nn] = (floatx4)0.f; accu[m][nn] = (floatx4)0.f; }

    for (int k0 = 0; k0 < HDIM; k0 += 64) {
        if (k0) __syncthreads();             // readers done before overwrite
#pragma unroll
        for (int c = 0; c < 4; ++c) dma16(asrc[c] + (size_t)k0 * 2, smA  + aldo[c]);
#pragma unroll
        for (int c = 0; c < 2; ++c) dma16(gsrc[c] + (size_t)k0 * 2, smBg + bldo[c]);
#pragma unroll
        for (int c = 0; c < 2; ++c) dma16(usrc[c] + (size_t)k0 * 2, smBu + bldo[c]);
        __syncthreads();                     // vmcnt(0) drain -> data visible
#pragma unroll
        for (int kk = 0; kk < 2; ++kk) {
            const int kA = kk * 64 + (lane >> 4) * 16;
            bf16x8 a[4], fg[2], fu[2];
#pragma unroll
            for (int m = 0; m < 4; ++m) {
                int row = wr * 64 + m * 16 + (lane & 15);
                a[m] = *reinterpret_cast<const bf16x8*>(smA + row * 128 + (kA ^ ((row & 7) << 4)));
            }
#pragma unroll
            for (int nn = 0; nn < 2; ++nn) {
                int cc = wc * 32 + nn * 16 + (lane & 15);
                int ad = cc * 128 + (kA ^ ((cc & 7) << 4));
                fg[nn] = *reinterpret_cast<const bf16x8*>(smBg + ad);
                fu[nn] = *reinterpret_cast<const bf16x8*>(smBu + ad);
            }
#pragma unroll
            for (int m = 0; m < 4; ++m)
#pragma unroll
                for (int nn = 0; nn < 2; ++nn) {
                    accg[m][nn] = __builtin_amdgcn_mfma_f32_16x16x32_bf16(a[m], fg[nn], accg[m][nn], 0, 0, 0);
                    accu[m][nn] = __builtin_amdgcn_mfma_f32_16x16x32_bf16(a[m], fu[nn], accu[m][nn], 0, 0, 0);
                }
        }
    }

    // epilogue: silu(gate) * up -> act (bf16)
#pragma unroll
    for (int m = 0; m < 4; ++m)
#pragma unroll
        for (int nn = 0; nn < 2; ++nn)
#pragma unroll
            for (int j = 0; j < 4; ++j) {
                int rr = wr * 64 + m * 16 + ((lane >> 4) << 2) + j;
                if (rr < nr) {
                    int f = c0 + wc * 32 + nn * 16 + (lane & 15);
                    float gg = accg[m][nn][j];
                    float uu = accu[m][nn][j];
                    float s = gg / (1.f + __expf(-gg));
                    act[(size_t)(p0 + rr) * FDIM + f] = f2bf(s * uu);
                }
            }
}

// ---------------------------------------------------------------------------
// GEMM2: partial[slot][h] = w * (act_row . dp[e][h][:]), bf16 out.
// Block 128 rows x 128 h-cols; 4 waves (2x2), wave 64x64, acc[4][4].
// Single-buffer LDS (33KB -> 4 blocks/CU).
__global__ __launch_bounds__(256, 4) void k_gemm2(
    const unsigned short* __restrict__ act, const unsigned short* __restrict__ dpbf,
    const int* __restrict__ offsets, const int* __restrict__ perm_slot,
    const int* __restrict__ q2,
    const float* __restrict__ row_w, unsigned short* __restrict__ partial)
{
    const int bid = blockIdx.x;
    const int q = q2[(bid & 7) * Q2LEN + (bid >> 3)];   // XCD-local queue
    if (q < 0) return;
    const int e  = q & 15;
    const int rt = (q >> 4) & 31;
    const int c0 = (q >> 9) * 128;
    const int off_e = offsets[e];
    const int n_e   = offsets[e + 1] - off_e;
    const int p0 = off_e + rt * 128;
    const int nr = min(128, n_e - rt * 128);

    __shared__ __align__(16) char smA[128 * 128];
    __shared__ __align__(16) char smB[128 * 128];
    __shared__ int   sSlot[128];
    __shared__ float sW[128];

    const int t = threadIdx.x;
    const int lane = t & 63;
    const int wv = t >> 6;
    const int wr = wv >> 1, wc = wv & 1;
    if (t < 128) {
        int p = min(p0 + t, NKROWS - 1);
        sSlot[t] = perm_slot[p];
        sW[t]    = row_w[p];
    }
    __syncthreads();

    const int rin = lane >> 3;
    const int pre = ((lane & 7) << 4) ^ (rin << 4);

    const char* asrc[4];
    int aldo[4];
#pragma unroll
    for (int c = 0; c < 4; ++c) {
        int ch = wv * 4 + c;
        int row = ch * 8 + rin;
        int p = min(p0 + row, NKROWS - 1);
        asrc[c] = (const char*)(act + (size_t)p * FDIM) + pre;
        aldo[c] = ch * 1024;
    }
    const unsigned short* dpE = dpbf + (size_t)e * HDIM * FDIM;
    const char* bsrc[4];
    int bldo[4];
#pragma unroll
    for (int c = 0; c < 4; ++c) {
        int ch = wv * 4 + c;
        int col = ch * 8 + rin;
        bsrc[c] = (const char*)(dpE + (size_t)(c0 + col) * FDIM) + pre;
        bldo[c] = ch * 1024;
    }

    floatx4 acc[4][4];
#pragma unroll
    for (int m = 0; m < 4; ++m)
#pragma unroll
        for (int nn = 0; nn < 4; ++nn) acc[m][nn] = (floatx4)0.f;

    for (int k0 = 0; k0 < FDIM; k0 += 64) {
        if (k0) __syncthreads();
#pragma unroll
        for (int c = 0; c < 4; ++c) dma16(asrc[c] + (size_t)k0 * 2, smA + aldo[c]);
#pragma unroll
        for (int c = 0; c < 4; ++c) dma16(bsrc[c] + (size_t)k0 * 2, smB + bldo[c]);
        __syncthreads();
#pragma unroll
        for (int kk = 0; kk < 2; ++kk) {
            const int kA = kk * 64 + (lane >> 4) * 16;
            bf16x8 a[4], fb[4];
#pragma unroll
            for (int m = 0; m < 4; ++m) {
                int row = wr * 64 + m * 16 + (lane & 15);
                a[m] = *reinterpret_cast<const bf16x8*>(smA + row * 128 + (kA ^ ((row & 7) << 4)));
            }
#pragma unroll
            for (int nn = 0; nn < 4; ++nn) {
                int cc = wc * 64 + nn * 16 + (lane & 15);
                fb[nn] = *reinterpret_cast<const bf16x8*>(smB + cc * 128 + (kA ^ ((cc & 7) << 4)));
            }
#pragma unroll
            for (int m = 0; m < 4; ++m)
#pragma unroll
                for (int nn = 0; nn < 4; ++nn)
                    acc[m][nn] = __builtin_amdgcn_mfma_f32_16x16x32_bf16(a[m], fb[nn], acc[m][nn], 0, 0, 0);
        }
    }

#pragma unroll
    for (int m = 0; m < 4; ++m)
#pragma unroll
        for (int nn = 0; nn < 4; ++nn)
#pragma unroll
            for (int j = 0; j < 4; ++j) {
                int rr = wr * 64 + m * 16 + ((lane >> 4) << 2) + j;
                if (rr < nr) {
                    int hcol = c0 + wc * 64 + nn * 16 + (lane & 15);
                    partial[(size_t)sSlot[rr] * HDIM + hcol] = f2bf(sW[rr] * acc[m][nn][j]);
                }
            }
}

// ---------------------------------------------------------------------------
// out[n][h] = partial[2n][h] + partial[2n+1][h]  (bf16 -> fp32)
__global__ __launch_bounds__(256) void k_combine(
    const unsigned short* __restrict__ partial, float* __restrict__ out)
{
    int gid = blockIdx.x * 256 + threadIdx.x;   // NTOK * H / 8 = 262144
    int n = gid >> 7;
    int r = gid & 127;
    uint4 a = reinterpret_cast<const uint4*>(partial + (size_t)(2 * n) * HDIM)[r];
    uint4 b = reinterpret_cast<const uint4*>(partial + (size_t)(2 * n + 1) * HDIM)[r];
    float4 o0, o1;
    o0.x = bf2f(a.x & 0xFFFF) + bf2f(b.x & 0xFFFF);
    o0.y = bf2f(a.x >> 16)    + bf2f(b.x >> 16);
    o0.z = bf2f(a.y & 0xFFFF) + bf2f(b.y & 0xFFFF);
    o0.w = bf2f(a.y >> 16)    + bf2f(b.y >> 16);
    o1.x = bf2f(a.z & 0xFFFF) + bf2f(b.z & 0xFFFF);
    o1.y = bf2f(a.z >> 16)    + bf2f(b.z >> 16);
    o1.z = bf2f(a.w & 0xFFFF) + bf2f(b.w & 0xFFFF);
    o1.w = bf2f(a.w >> 16)    + bf2f(b.w >> 16);
    float4* op = reinterpret_cast<float4*>(out + (size_t)n * HDIM + r * 8);
    op[0] = o0;
    op[1] = o1;
}

// ---------------------------------------------------------------------------
extern "C" void kernel_launch(void* const* d_in, const int* in_sizes, int n_in,
                              void* d_out, int out_size, void* d_ws, size_t ws_size,
                              hipStream_t stream)
{
    const float* h  = (const float*)d_in[0];
    const float* rw = (const float*)d_in[1];
    const float* gu = (const float*)d_in[2];
    const float* dp = (const float*)d_in[3];
    float* out = (float*)d_out;

    char* ws = (char*)d_ws;
    int*            topk_idx  = (int*)   (ws + 0);
    float*          topk_w    = (float*) (ws + 16384);
    int*            offsets   = (int*)   (ws + 32768);
    int*            perm_slot = (int*)   (ws + 36864);
    float*          row_w     = (float*) (ws + 53248);
    int*            q1        = (int*)   (ws + 69632);   // 8*256*4 = 8192 B
    int*            q2        = (int*)   (ws + 77824);   // 8*128*4 = 4096 B
    unsigned short* hbf       = (unsigned short*)(ws + (1u  << 20));  // 8MB
    unsigned short* partial   = (unsigned short*)(ws + (1u  << 20));  // overlays hbf (dead after gemm1)
    unsigned short* act       = (unsigned short*)(ws + (9u  << 20));  // 8MB
    unsigned short* gubf      = (unsigned short*)(ws + (17u << 20));  // 32MB
    unsigned short* dpbf      = (unsigned short*)(ws + (49u << 20));  // 16MB

    hipLaunchKernelGGL(k_pre,        dim3(2048),      dim3(256), 0, stream, gu, gubf, dp, dpbf, h, rw, hbf, topk_idx, topk_w);
    hipLaunchKernelGGL(k_build_perm, dim3(1),         dim3(256), 0, stream, topk_idx, topk_w, offsets, perm_slot, row_w, q1, q2);
    hipLaunchKernelGGL(k_gemm1,      dim3(8 * Q1LEN), dim3(256), 0, stream, hbf, gubf, offsets, perm_slot, q1, act);
    hipLaunchKernelGGL(k_gemm2,      dim3(8 * Q2LEN), dim3(256), 0, stream, act, dpbf, offsets, perm_slot, q2, row_w, partial);
    hipLaunchKernelGGL(k_combine,    dim3(1024),      dim3(256), 0, stream, partial, out);
}

// Round 11
// 92.863 us; speedup vs baseline: 1.7054x; 1.0603x over previous
//
#include <hip/hip_runtime.h>

// ---------------------------------------------------------------------------
// FakeFusedMoE: E=8, H=1024, F=1024, top-2, N=2048 tokens (4096 routed rows).
// Sparse grouped-GEMM MoE, bf16 MFMA. NO weight pre-convert pass:
//   k_router    : logits -> top2 (analytic renorm) + hidden fp32->bf16
//   k_build_perm: counting-sort + per-XCD work queues (parallel build)
//   k_gemm1/2   : single-buffer 2-barrier GEMMs, 3 blocks/CU; A bf16 via DMA,
//                 B = fp32 weights DMA'd directly into LDS (pre-swizzled
//                 source), converted to bf16 fragments at LDS-read time.
//                 Per-XCD col-major queues keep A/B panel re-reads L2-local.
//   k_combine   : out[n] = partial[2n] + partial[2n+1]
// ---------------------------------------------------------------------------

#define NTOK   2048
#define HDIM   1024
#define FDIM   1024
#define NEXP   8
#define NKROWS 4096
#define Q1LEN  256    // per-XCD gemm1 queue (16 cols x up to 16 row tiles)
#define Q2LEN  128    // per-XCD gemm2 queue (8 cols x up to 16 row tiles)

typedef __attribute__((ext_vector_type(8))) __bf16 bf16x8;
typedef __attribute__((ext_vector_type(4))) float  floatx4;

__device__ __forceinline__ unsigned short f2bf(float x) {
    unsigned int u = __builtin_bit_cast(unsigned int, x);
    u += 0x7FFFu + ((u >> 16) & 1u);
    return (unsigned short)(u >> 16);
}

__device__ __forceinline__ float bf2f(unsigned short v) {
    unsigned int u = (unsigned int)v << 16;
    return __builtin_bit_cast(float, u);
}

// 8x fp32 -> bf16x8 fragment (v_cvt_pk_bf16_f32 pairs)
__device__ __forceinline__ bf16x8 cvt8(float4 a, float4 b) {
    bf16x8 r;
    r[0] = (__bf16)a.x; r[1] = (__bf16)a.y; r[2] = (__bf16)a.z; r[3] = (__bf16)a.w;
    r[4] = (__bf16)b.x; r[5] = (__bf16)b.y; r[6] = (__bf16)b.z; r[7] = (__bf16)b.w;
    return r;
}

// async global->LDS, 16B/lane; LDS dest = wave-uniform base + lane*16
__device__ __forceinline__ void dma16(const void* g, void* l) {
    __builtin_amdgcn_global_load_lds(
        (const __attribute__((address_space(1))) unsigned int*)g,
        (__attribute__((address_space(3))) unsigned int*)l, 16, 0, 0);
}

// ---------------------------------------------------------------------------
// Router + hidden fp32->bf16 conversion. One wave per token.
__global__ __launch_bounds__(256) void k_router(
    const float* __restrict__ h, const float* __restrict__ rw,
    unsigned short* __restrict__ hbf,
    int* __restrict__ topk_idx, float* __restrict__ topk_w)
{
    const int lane = threadIdx.x & 63;
    const int wave = threadIdx.x >> 6;
    const int n = blockIdx.x * 4 + wave;

    const float4* hp = reinterpret_cast<const float4*>(h + (size_t)n * HDIM);
    uint2* hb = reinterpret_cast<uint2*>(hbf + (size_t)n * HDIM);
    float acc[NEXP];
#pragma unroll
    for (int e = 0; e < NEXP; ++e) acc[e] = 0.f;

#pragma unroll
    for (int i0 = 0; i0 < HDIM / 4; i0 += 64) {
        float4 hv = hp[i0 + lane];
        uint2 o;
        o.x = (unsigned)f2bf(hv.x) | ((unsigned)f2bf(hv.y) << 16);
        o.y = (unsigned)f2bf(hv.z) | ((unsigned)f2bf(hv.w) << 16);
        hb[i0 + lane] = o;
#pragma unroll
        for (int e = 0; e < NEXP; ++e) {
            float4 rv = reinterpret_cast<const float4*>(rw + e * HDIM)[i0 + lane];
            acc[e] += hv.x * rv.x + hv.y * rv.y + hv.z * rv.z + hv.w * rv.w;
        }
    }
#pragma unroll
    for (int e = 0; e < NEXP; ++e) {
#pragma unroll
        for (int off = 32; off > 0; off >>= 1)
            acc[e] += __shfl_xor(acc[e], off);
    }
    if (lane == 0) {
        int i0 = 0; float m0 = acc[0];
        for (int e = 1; e < NEXP; ++e) if (acc[e] > m0) { m0 = acc[e]; i0 = e; }
        int i1 = -1; float m1 = -3.0e38f;
        for (int e = 0; e < NEXP; ++e) if (e != i0 && acc[e] > m1) { m1 = acc[e]; i1 = e; }
        float d  = __expf(m1 - m0);
        float w0 = 1.f / (1.f + d);
        topk_idx[n * 2 + 0] = i0;
        topk_idx[n * 2 + 1] = i1;
        topk_w [n * 2 + 0] = w0;
        topk_w [n * 2 + 1] = 1.f - w0;
    }
}

// ---------------------------------------------------------------------------
// Counting-sort permutation + per-XCD work queues (parallel build).
// Queue entry: e | (rowTile<<4) | (colTile<<9); -1 = empty.
__global__ __launch_bounds__(256) void k_build_perm(
    const int* __restrict__ topk_idx, const float* __restrict__ topk_w,
    int* __restrict__ offsets, int* __restrict__ perm_slot, float* __restrict__ row_w,
    int* __restrict__ q1, int* __restrict__ q2)
{
    __shared__ int cnt[NEXP];
    __shared__ int cur[NEXP];
    __shared__ int off[NEXP + 1];
    const int t = threadIdx.x;
    if (t < NEXP) cnt[t] = 0;
    __syncthreads();
    for (int s = t; s < NKROWS; s += 256) atomicAdd(&cnt[topk_idx[s]], 1);
    __syncthreads();
    if (t == 0) {
        int a = 0;
        for (int e = 0; e < NEXP; ++e) { off[e] = a; a += cnt[e]; cur[e] = off[e]; }
        off[NEXP] = a;
    }
    __syncthreads();
    for (int i = t; i < NEXP * Q1LEN; i += 256) {
        int e = i >> 8;                    // Q1LEN = 256
        int j = i & (Q1LEN - 1);
        int rts = (cnt[e] + 127) >> 7;
        int v = -1;
        if (j < 16 * rts) { int col = j / rts; int r = j - col * rts; v = e | (r << 4) | (col << 9); }
        q1[i] = v;
    }
    for (int i = t; i < NEXP * Q2LEN; i += 256) {
        int e = i >> 7;                    // Q2LEN = 128
        int j = i & (Q2LEN - 1);
        int rts = (cnt[e] + 127) >> 7;
        int v = -1;
        if (j < 8 * rts) { int col = j / rts; int r = j - col * rts; v = e | (r << 4) | (col << 9); }
        q2[i] = v;
    }
    for (int s = t; s < NKROWS; s += 256) {
        int e = topk_idx[s];
        int pos = atomicAdd(&cur[e], 1);
        perm_slot[pos] = s;
        row_w[pos] = topk_w[s];
    }
    if (t < NEXP + 1) offsets[t] = off[t];
}

// ---------------------------------------------------------------------------
// GEMM1: act[p][f] = silu(gate)*up. Block 128 rows x 64 f-values (gate AND up).
// 4 waves (2x2). Single-buffer LDS (48KB -> 3 blocks/CU), 2 barriers/step.
// A: bf16 DMA (pre-swizzled source). Bg/Bu: fp32 DMA, cvt->bf16 at read.
__global__ __launch_bounds__(256, 3) void k_gemm1(
    const unsigned short* __restrict__ hbf, const float* __restrict__ gu,
    const int* __restrict__ offsets, const int* __restrict__ perm_slot,
    const int* __restrict__ q1,
    unsigned short* __restrict__ act)
{
    const int bid = blockIdx.x;
    const int q = q1[(bid & 7) * Q1LEN + (bid >> 3)];   // XCD-local queue
    if (q < 0) return;
    const int e  = q & 15;
    const int rt = (q >> 4) & 31;
    const int c0 = (q >> 9) * 64;
    const int off_e = offsets[e];
    const int n_e   = offsets[e + 1] - off_e;
    const int p0 = off_e + rt * 128;
    const int nr = min(128, n_e - rt * 128);

    __shared__ __align__(16) char smA [128 * 128];   // bf16 128r x 64K
    __shared__ __align__(16) char smBg[64 * 256];    // fp32 64c x 64K
    __shared__ __align__(16) char smBu[64 * 256];
    __shared__ int sTok[128];

    const int t = threadIdx.x;
    const int lane = t & 63;
    const int wv = t >> 6;
    const int wr = wv >> 1, wc = wv & 1;
    if (t < 128) sTok[t] = perm_slot[min(p0 + t, NKROWS - 1)] >> 1;
    __syncthreads();

    // A-DMA: chunk ch = wv*4+c covers rows ch*8..+8 (128B bf16 each)
    const int rin = lane >> 3;
    const int preA = ((lane & 7) << 4) ^ (rin << 4);
    const char* asrc[4];
    int aldo[4];
#pragma unroll
    for (int c = 0; c < 4; ++c) {
        int ch = wv * 4 + c;
        int row = ch * 8 + rin;
        asrc[c] = (const char*)(hbf + (size_t)sTok[row] * HDIM) + preA;
        aldo[c] = ch * 1024;
    }
    // B-DMA (fp32): chunk ch = wv*4+c covers 4 rows (256B each), 16 chunks/64 rows
    const float* guE = gu + (size_t)e * (2 * FDIM) * HDIM;
    const char* gsrc[4];
    const char* usrc[4];
    int bldo[4];
#pragma unroll
    for (int c = 0; c < 4; ++c) {
        int ch = wv * 4 + c;
        int row = ch * 4 + (lane >> 4);
        int pre = ((lane & 15) << 4) ^ ((row & 7) << 4);
        gsrc[c] = (const char*)(guE + (size_t)(c0 + row) * HDIM) + pre;
        usrc[c] = (const char*)(guE + (size_t)(FDIM + c0 + row) * HDIM) + pre;
        bldo[c] = ch * 1024;
    }

    floatx4 accg[4][2], accu[4][2];
#pragma unroll
    for (int m = 0; m < 4; ++m)
#pragma unroll
        for (int nn = 0; nn < 2; ++nn) { accg[m][nn] = (floatx4)0.f; accu[m][nn] = (floatx4)0.f; }

    for (int k0 = 0; k0 < HDIM; k0 += 64) {
        if (k0) __syncthreads();             // readers done before overwrite
#pragma unroll
        for (int c = 0; c < 4; ++c) dma16(asrc[c] + (size_t)k0 * 2, smA  + aldo[c]);
#pragma unroll
        for (int c = 0; c < 4; ++c) dma16(gsrc[c] + (size_t)k0 * 4, smBg + bldo[c]);
#pragma unroll
        for (int c = 0; c < 4; ++c) dma16(usrc[c] + (size_t)k0 * 4, smBu + bldo[c]);
        __syncthreads();                     // vmcnt(0) drain -> data visible
#pragma unroll
        for (int kk = 0; kk < 2; ++kk) {
            const int kA = kk * 64 + (lane >> 4) * 16;
            const int kB = kk * 128 + (lane >> 4) * 32;
            bf16x8 a[4], fg[2], fu[2];
#pragma unroll
            for (int m = 0; m < 4; ++m) {
                int row = wr * 64 + m * 16 + (lane & 15);
                a[m] = *reinterpret_cast<const bf16x8*>(smA + row * 128 + (kA ^ ((row & 7) << 4)));
            }
#pragma unroll
            for (int nn = 0; nn < 2; ++nn) {
                int cc = wc * 32 + nn * 16 + (lane & 15);
                int b0 = cc * 256 + (kB ^ ((cc & 7) << 4));
                int b1 = cc * 256 + ((kB + 16) ^ ((cc & 7) << 4));
                fg[nn] = cvt8(*reinterpret_cast<const float4*>(smBg + b0),
                              *reinterpret_cast<const float4*>(smBg + b1));
                fu[nn] = cvt8(*reinterpret_cast<const float4*>(smBu + b0),
                              *reinterpret_cast<const float4*>(smBu + b1));
            }
#pragma unroll
            for (int m = 0; m < 4; ++m)
#pragma unroll
                for (int nn = 0; nn < 2; ++nn) {
                    accg[m][nn] = __builtin_amdgcn_mfma_f32_16x16x32_bf16(a[m], fg[nn], accg[m][nn], 0, 0, 0);
                    accu[m][nn] = __builtin_amdgcn_mfma_f32_16x16x32_bf16(a[m], fu[nn], accu[m][nn], 0, 0, 0);
                }
        }
    }

    // epilogue: silu(gate) * up -> act (bf16)
#pragma unroll
    for (int m = 0; m < 4; ++m)
#pragma unroll
        for (int nn = 0; nn < 2; ++nn)
#pragma unroll
            for (int j = 0; j < 4; ++j) {
                int rr = wr * 64 + m * 16 + ((lane >> 4) << 2) + j;
                if (rr < nr) {
                    int f = c0 + wc * 32 + nn * 16 + (lane & 15);
                    float gg = accg[m][nn][j];
                    float uu = accu[m][nn][j];
                    float s = gg / (1.f + __expf(-gg));
                    act[(size_t)(p0 + rr) * FDIM + f] = f2bf(s * uu);
                }
            }
}

// ---------------------------------------------------------------------------
// GEMM2: partial[slot][h] = w * (act_row . dp[e][h][:]), bf16 out.
// Block 128 rows x 128 h-cols; 4 waves (2x2), wave 64x64, acc[4][4].
// A bf16 DMA; B fp32 DMA, cvt at read. LDS 48KB -> 3 blocks/CU.
__global__ __launch_bounds__(256, 3) void k_gemm2(
    const unsigned short* __restrict__ act, const float* __restrict__ dp,
    const int* __restrict__ offsets, const int* __restrict__ perm_slot,
    const int* __restrict__ q2,
    const float* __restrict__ row_w, unsigned short* __restrict__ partial)
{
    const int bid = blockIdx.x;
    const int q = q2[(bid & 7) * Q2LEN + (bid >> 3)];   // XCD-local queue
    if (q < 0) return;
    const int e  = q & 15;
    const int rt = (q >> 4) & 31;
    const int c0 = (q >> 9) * 128;
    const int off_e = offsets[e];
    const int n_e   = offsets[e + 1] - off_e;
    const int p0 = off_e + rt * 128;
    const int nr = min(128, n_e - rt * 128);

    __shared__ __align__(16) char smA[128 * 128];    // bf16 128r x 64K
    __shared__ __align__(16) char smB[128 * 256];    // fp32 128c x 64K
    __shared__ int   sSlot[128];
    __shared__ float sW[128];

    const int t = threadIdx.x;
    const int lane = t & 63;
    const int wv = t >> 6;
    const int wr = wv >> 1, wc = wv & 1;
    if (t < 128) {
        int p = min(p0 + t, NKROWS - 1);
        sSlot[t] = perm_slot[p];
        sW[t]    = row_w[p];
    }
    __syncthreads();

    const int rin = lane >> 3;
    const int preA = ((lane & 7) << 4) ^ (rin << 4);

    const char* asrc[4];
    int aldo[4];
#pragma unroll
    for (int c = 0; c < 4; ++c) {
        int ch = wv * 4 + c;
        int row = ch * 8 + rin;
        int p = min(p0 + row, NKROWS - 1);
        asrc[c] = (const char*)(act + (size_t)p * FDIM) + preA;
        aldo[c] = ch * 1024;
    }
    // B-DMA (fp32): 32 chunks of 4 rows (1KB each); 8 chunks per wave
    const float* dpE = dp + (size_t)e * HDIM * FDIM;
    const char* bsrc[8];
    int bldo[8];
#pragma unroll
    for (int c = 0; c < 8; ++c) {
        int ch = wv * 8 + c;
        int row = ch * 4 + (lane >> 4);
        int pre = ((lane & 15) << 4) ^ ((row & 7) << 4);
        bsrc[c] = (const char*)(dpE + (size_t)(c0 + row) * FDIM) + pre;
        bldo[c] = ch * 1024;
    }

    floatx4 acc[4][4];
#pragma unroll
    for (int m = 0; m < 4; ++m)
#pragma unroll
        for (int nn = 0; nn < 4; ++nn) acc[m][nn] = (floatx4)0.f;

    for (int k0 = 0; k0 < FDIM; k0 += 64) {
        if (k0) __syncthreads();
#pragma unroll
        for (int c = 0; c < 4; ++c) dma16(asrc[c] + (size_t)k0 * 2, smA + aldo[c]);
#pragma unroll
        for (int c = 0; c < 8; ++c) dma16(bsrc[c] + (size_t)k0 * 4, smB + bldo[c]);
        __syncthreads();
#pragma unroll
        for (int kk = 0; kk < 2; ++kk) {
            const int kA = kk * 64 + (lane >> 4) * 16;
            const int kB = kk * 128 + (lane >> 4) * 32;
            bf16x8 a[4], fb[4];
#pragma unroll
            for (int m = 0; m < 4; ++m) {
                int row = wr * 64 + m * 16 + (lane & 15);
                a[m] = *reinterpret_cast<const bf16x8*>(smA + row * 128 + (kA ^ ((row & 7) << 4)));
            }
#pragma unroll
            for (int nn = 0; nn < 4; ++nn) {
                int cc = wc * 64 + nn * 16 + (lane & 15);
                int b0 = cc * 256 + (kB ^ ((cc & 7) << 4));
                int b1 = cc * 256 + ((kB + 16) ^ ((cc & 7) << 4));
                fb[nn] = cvt8(*reinterpret_cast<const float4*>(smB + b0),
                              *reinterpret_cast<const float4*>(smB + b1));
            }
#pragma unroll
            for (int m = 0; m < 4; ++m)
#pragma unroll
                for (int nn = 0; nn < 4; ++nn)
                    acc[m][nn] = __builtin_amdgcn_mfma_f32_16x16x32_bf16(a[m], fb[nn], acc[m][nn], 0, 0, 0);
        }
    }

#pragma unroll
    for (int m = 0; m < 4; ++m)
#pragma unroll
        for (int nn = 0; nn < 4; ++nn)
#pragma unroll
            for (int j = 0; j < 4; ++j) {
                int rr = wr * 64 + m * 16 + ((lane >> 4) << 2) + j;
                if (rr < nr) {
                    int hcol = c0 + wc * 64 + nn * 16 + (lane & 15);
                    partial[(size_t)sSlot[rr] * HDIM + hcol] = f2bf(sW[rr] * acc[m][nn][j]);
                }
            }
}

// ---------------------------------------------------------------------------
// out[n][h] = partial[2n][h] + partial[2n+1][h]  (bf16 -> fp32)
__global__ __launch_bounds__(256) void k_combine(
    const unsigned short* __restrict__ partial, float* __restrict__ out)
{
    int gid = blockIdx.x * 256 + threadIdx.x;   // NTOK * H / 8 = 262144
    int n = gid >> 7;
    int r = gid & 127;
    uint4 a = reinterpret_cast<const uint4*>(partial + (size_t)(2 * n) * HDIM)[r];
    uint4 b = reinterpret_cast<const uint4*>(partial + (size_t)(2 * n + 1) * HDIM)[r];
    float4 o0, o1;
    o0.x = bf2f(a.x & 0xFFFF) + bf2f(b.x & 0xFFFF);
    o0.y = bf2f(a.x >> 16)    + bf2f(b.x >> 16);
    o0.z = bf2f(a.y & 0xFFFF) + bf2f(b.y & 0xFFFF);
    o0.w = bf2f(a.y >> 16)    + bf2f(b.y >> 16);
    o1.x = bf2f(a.z & 0xFFFF) + bf2f(b.z & 0xFFFF);
    o1.y = bf2f(a.z >> 16)    + bf2f(b.z >> 16);
    o1.z = bf2f(a.w & 0xFFFF) + bf2f(b.w & 0xFFFF);
    o1.w = bf2f(a.w >> 16)    + bf2f(b.w >> 16);
    float4* op = reinterpret_cast<float4*>(out + (size_t)n * HDIM + r * 8);
    op[0] = o0;
    op[1] = o1;
}

// ---------------------------------------------------------------------------
extern "C" void kernel_launch(void* const* d_in, const int* in_sizes, int n_in,
                              void* d_out, int out_size, void* d_ws, size_t ws_size,
                              hipStream_t stream)
{
    const float* h  = (const float*)d_in[0];
    const float* rw = (const float*)d_in[1];
    const float* gu = (const float*)d_in[2];
    const float* dp = (const float*)d_in[3];
    float* out = (float*)d_out;

    char* ws = (char*)d_ws;
    int*            topk_idx  = (int*)   (ws + 0);
    float*          topk_w    = (float*) (ws + 16384);
    int*            offsets   = (int*)   (ws + 32768);
    int*            perm_slot = (int*)   (ws + 36864);
    float*          row_w     = (float*) (ws + 53248);
    int*            q1        = (int*)   (ws + 69632);   // 8*256*4 = 8192 B
    int*            q2        = (int*)   (ws + 77824);   // 8*128*4 = 4096 B
    unsigned short* hbf       = (unsigned short*)(ws + (1u  << 20));  // 8MB
    unsigned short* partial   = (unsigned short*)(ws + (1u  << 20));  // overlays hbf (dead after gemm1)
    unsigned short* act       = (unsigned short*)(ws + (9u  << 20));  // 8MB

    hipLaunchKernelGGL(k_router,     dim3(512),       dim3(256), 0, stream, h, rw, hbf, topk_idx, topk_w);
    hipLaunchKernelGGL(k_build_perm, dim3(1),         dim3(256), 0, stream, topk_idx, topk_w, offsets, perm_slot, row_w, q1, q2);
    hipLaunchKernelGGL(k_gemm1,      dim3(8 * Q1LEN), dim3(256), 0, stream, hbf, gu, offsets, perm_slot, q1, act);
    hipLaunchKernelGGL(k_gemm2,      dim3(8 * Q2LEN), dim3(256), 0, stream, act, dp, offsets, perm_slot, q2, row_w, partial);
    hipLaunchKernelGGL(k_combine,    dim3(1024),      dim3(256), 0, stream, partial, out);
}